// Round 1
// baseline (557.666 us; speedup 1.0000x reference)
//
#include <hip/hip_runtime.h>
#include <math.h>

#define NN 50000
#define EE 800000
#define E2 (EE + NN)
#define FIN 128
#define HC 256
#define HID 128
#define NCLS 10
#define NEG 0.2f

// ---------------- GEMM: out[M x NC] = A[M x K] @ W[K x NC], 32 rows/block ----------------
template<int K, int NC>
__global__ __launch_bounds__(256) void gemm32(const float* __restrict__ A,
                                              const float* __restrict__ W,
                                              float* __restrict__ out, int M) {
    constexpr int CL  = NC / 4;    // column-lane count (threads along N, 4 cols each)
    constexpr int RG  = 256 / CL;  // row groups
    constexpr int RPG = 32 / RG;   // rows per thread
    __shared__ float xs[32][K];
    const int row0 = blockIdx.x * 32;
    const int t = threadIdx.x;

    // cooperative tile load (float4)
    for (int idx = t; idx < 32 * (K / 4); idx += 256) {
        int r = idx / (K / 4), k4 = idx % (K / 4);
        int row = row0 + r;
        float4 v = (row < M) ? ((const float4*)A)[(size_t)row * (K / 4) + k4]
                             : make_float4(0.f, 0.f, 0.f, 0.f);
        ((float4*)&xs[r][0])[k4] = v;
    }
    __syncthreads();

    const int tc = t % CL;
    const int tr = t / CL;
    float acc[RPG][4];
#pragma unroll
    for (int r = 0; r < RPG; ++r) { acc[r][0]=0.f; acc[r][1]=0.f; acc[r][2]=0.f; acc[r][3]=0.f; }

    const float4* Wv = (const float4*)W;
    for (int k = 0; k < K; k += 4) {
        float4 w0 = Wv[(k + 0) * CL + tc];
        float4 w1 = Wv[(k + 1) * CL + tc];
        float4 w2 = Wv[(k + 2) * CL + tc];
        float4 w3 = Wv[(k + 3) * CL + tc];
#pragma unroll
        for (int r = 0; r < RPG; ++r) {
            float4 xv = *(const float4*)&xs[tr * RPG + r][k];
            acc[r][0] += xv.x * w0.x + xv.y * w1.x + xv.z * w2.x + xv.w * w3.x;
            acc[r][1] += xv.x * w0.y + xv.y * w1.y + xv.z * w2.y + xv.w * w3.y;
            acc[r][2] += xv.x * w0.z + xv.y * w1.z + xv.z * w2.z + xv.w * w3.z;
            acc[r][3] += xv.x * w0.w + xv.y * w1.w + xv.z * w2.w + xv.w * w3.w;
        }
    }
#pragma unroll
    for (int r = 0; r < RPG; ++r) {
        int row = row0 + tr * RPG + r;
        if (row < M)
            ((float4*)out)[(size_t)row * (NC / 4) + tc] =
                make_float4(acc[r][0], acc[r][1], acc[r][2], acc[r][3]);
    }
}

// ---------------- attention coefficients: a_s/a_d [N,4] ----------------
__global__ __launch_bounds__(256) void att_kernel(const float* __restrict__ h,
                                                  const float* __restrict__ att_s,
                                                  const float* __restrict__ att_d,
                                                  float* __restrict__ a_s,
                                                  float* __restrict__ a_d) {
    int node = blockIdx.x * 4 + (threadIdx.x >> 6);
    int lane = threadIdx.x & 63;
    if (node >= NN) return;
    const float* hr = h + (size_t)node * HC;
    float ps[4], pd[4];
#pragma unroll
    for (int hd = 0; hd < 4; ++hd) {
        float v = hr[hd * 64 + lane];
        ps[hd] = v * att_s[hd * 64 + lane];
        pd[hd] = v * att_d[hd * 64 + lane];
    }
#pragma unroll
    for (int m = 32; m >= 1; m >>= 1) {
#pragma unroll
        for (int hd = 0; hd < 4; ++hd) {
            ps[hd] += __shfl_xor(ps[hd], m, 64);
            pd[hd] += __shfl_xor(pd[hd], m, 64);
        }
    }
    if (lane == 0) {
#pragma unroll
        for (int hd = 0; hd < 4; ++hd) {
            a_s[node * 4 + hd] = ps[hd];
            a_d[node * 4 + hd] = pd[hd];
        }
    }
}

// ---------------- CSR build ----------------
__global__ __launch_bounds__(256) void deg_kernel(const int* __restrict__ ei, int* __restrict__ deg) {
    int e = blockIdx.x * 256 + threadIdx.x;
    if (e < EE) atomicAdd(&deg[ei[EE + e]], 1);
}

__global__ __launch_bounds__(256) void scan_a(const int* __restrict__ deg, int* __restrict__ row_start,
                                              int* __restrict__ blocksum) {
    __shared__ int sh[256];
    int t = threadIdx.x;
    int i = blockIdx.x * 256 + t;
    int v = (i < NN) ? (deg[i] + 1) : 0;   // +1 self loop
    sh[t] = v;
    __syncthreads();
#pragma unroll
    for (int off = 1; off < 256; off <<= 1) {
        int y = (t >= off) ? sh[t - off] : 0;
        __syncthreads();
        sh[t] += y;
        __syncthreads();
    }
    if (i < NN) row_start[i] = sh[t] - v;  // local exclusive
    if (t == 255) blocksum[blockIdx.x] = sh[255];
}

__global__ __launch_bounds__(256) void scan_b(int* __restrict__ bs, int nb) {
    __shared__ int sh[256];
    int t = threadIdx.x;
    int v = (t < nb) ? bs[t] : 0;
    sh[t] = v;
    __syncthreads();
#pragma unroll
    for (int off = 1; off < 256; off <<= 1) {
        int y = (t >= off) ? sh[t - off] : 0;
        __syncthreads();
        sh[t] += y;
        __syncthreads();
    }
    if (t < nb) bs[t] = sh[t] - v;  // exclusive block offsets
}

__global__ __launch_bounds__(256) void scan_c(int* __restrict__ row_start, const int* __restrict__ bs) {
    int i = blockIdx.x * 256 + threadIdx.x;
    if (i < NN) row_start[i] += bs[blockIdx.x];
    if (i == 0) row_start[NN] = E2;
}

__global__ __launch_bounds__(256) void scatter_kernel(const int* __restrict__ ei,
                                                      const int* __restrict__ row_start,
                                                      int* __restrict__ cursor,
                                                      int* __restrict__ csr_src) {
    int e = blockIdx.x * 256 + threadIdx.x;
    if (e >= E2) return;
    int src, dst;
    if (e < EE) { src = ei[e]; dst = ei[EE + e]; }
    else        { src = dst = e - EE; }
    int pos = row_start[dst] + atomicAdd(&cursor[dst], 1);
    csr_src[pos] = src;
}

// ---------------- fused GAT: softmax + aggregation + ELU, one wave per node ----------------
__global__ __launch_bounds__(256) void gat_kernel(const float* __restrict__ h,
                                                  const float* __restrict__ a_s,
                                                  const float* __restrict__ a_d,
                                                  const int* __restrict__ row_start,
                                                  const int* __restrict__ csr_src,
                                                  const float* __restrict__ bg,
                                                  float* __restrict__ xg,
                                                  float* __restrict__ dinv) {
    int node = blockIdx.x * 4 + (threadIdx.x >> 6);
    int lane = threadIdx.x & 63;
    if (node >= NN) return;
    int s0 = row_start[node], s1 = row_start[node + 1];
    float4 ad = ((const float4*)a_d)[node];

    float mx0 = -1e30f, mx1 = -1e30f, mx2 = -1e30f, mx3 = -1e30f;
    for (int e = s0; e < s1; ++e) {
        int src = csr_src[e];
        float4 as = ((const float4*)a_s)[src];
        float v0 = as.x + ad.x; v0 = v0 > 0.f ? v0 : NEG * v0; mx0 = fmaxf(mx0, v0);
        float v1 = as.y + ad.y; v1 = v1 > 0.f ? v1 : NEG * v1; mx1 = fmaxf(mx1, v1);
        float v2 = as.z + ad.z; v2 = v2 > 0.f ? v2 : NEG * v2; mx2 = fmaxf(mx2, v2);
        float v3 = as.w + ad.w; v3 = v3 > 0.f ? v3 : NEG * v3; mx3 = fmaxf(mx3, v3);
    }
    float den0 = 0.f, den1 = 0.f, den2 = 0.f, den3 = 0.f;
    float acc0 = 0.f, acc1 = 0.f, acc2 = 0.f, acc3 = 0.f;
    for (int e = s0; e < s1; ++e) {
        int src = csr_src[e];
        float4 as = ((const float4*)a_s)[src];
        float v0 = as.x + ad.x; v0 = v0 > 0.f ? v0 : NEG * v0;
        float v1 = as.y + ad.y; v1 = v1 > 0.f ? v1 : NEG * v1;
        float v2 = as.z + ad.z; v2 = v2 > 0.f ? v2 : NEG * v2;
        float v3 = as.w + ad.w; v3 = v3 > 0.f ? v3 : NEG * v3;
        float e0 = __expf(v0 - mx0); den0 += e0;
        float e1 = __expf(v1 - mx1); den1 += e1;
        float e2 = __expf(v2 - mx2); den2 += e2;
        float e3 = __expf(v3 - mx3); den3 += e3;
        const float* hr = h + (size_t)src * HC;
        acc0 += e0 * hr[lane];
        acc1 += e1 * hr[64 + lane];
        acc2 += e2 * hr[128 + lane];
        acc3 += e3 * hr[192 + lane];
    }
    float* xr = xg + (size_t)node * HC;
    float o0 = acc0 / den0 + bg[lane];
    float o1 = acc1 / den1 + bg[64 + lane];
    float o2 = acc2 / den2 + bg[128 + lane];
    float o3 = acc3 / den3 + bg[192 + lane];
    xr[lane]       = o0 > 0.f ? o0 : __expf(o0) - 1.f;
    xr[64 + lane]  = o1 > 0.f ? o1 : __expf(o1) - 1.f;
    xr[128 + lane] = o2 > 0.f ? o2 : __expf(o2) - 1.f;
    xr[192 + lane] = o3 > 0.f ? o3 : __expf(o3) - 1.f;
    if (lane == 0) dinv[node] = rsqrtf((float)(s1 - s0));
}

// ---------------- GCN: xc = relu(sym-norm SpMM(xw) + bc), one wave per node ----------------
__global__ __launch_bounds__(256) void gcn_kernel(const float* __restrict__ xw,
                                                  const int* __restrict__ row_start,
                                                  const int* __restrict__ csr_src,
                                                  const float* __restrict__ dinv,
                                                  const float* __restrict__ bc,
                                                  float* __restrict__ xc) {
    int node = blockIdx.x * 4 + (threadIdx.x >> 6);
    int lane = threadIdx.x & 63;
    if (node >= NN) return;
    int s0 = row_start[node], s1 = row_start[node + 1];
    float di = dinv[node];
    float acc0 = 0.f, acc1 = 0.f;
    for (int e = s0; e < s1; ++e) {
        int src = csr_src[e];
        float w = dinv[src] * di;
        const float* xr = xw + (size_t)src * HID;
        acc0 += w * xr[lane];
        acc1 += w * xr[64 + lane];
    }
    float o0 = acc0 + bc[lane];
    float o1 = acc1 + bc[64 + lane];
    xc[(size_t)node * HID + lane]      = o0 > 0.f ? o0 : 0.f;
    xc[(size_t)node * HID + 64 + lane] = o1 > 0.f ? o1 : 0.f;
}

// ---------------- classifier + log_softmax, one wave per node ----------------
__global__ __launch_bounds__(256) void head_kernel(const float* __restrict__ xc,
                                                   const float* __restrict__ Wl,
                                                   const float* __restrict__ bl,
                                                   float* __restrict__ out) {
    int node = blockIdx.x * 4 + (threadIdx.x >> 6);
    int lane = threadIdx.x & 63;
    if (node >= NN) return;
    float x0 = xc[(size_t)node * HID + lane];
    float x1 = xc[(size_t)node * HID + 64 + lane];
    float p[NCLS];
#pragma unroll
    for (int j = 0; j < NCLS; ++j)
        p[j] = x0 * Wl[lane * NCLS + j] + x1 * Wl[(64 + lane) * NCLS + j];
#pragma unroll
    for (int m = 32; m >= 1; m >>= 1) {
#pragma unroll
        for (int j = 0; j < NCLS; ++j) p[j] += __shfl_xor(p[j], m, 64);
    }
#pragma unroll
    for (int j = 0; j < NCLS; ++j) p[j] += bl[j];
    float mx = p[0];
#pragma unroll
    for (int j = 1; j < NCLS; ++j) mx = fmaxf(mx, p[j]);
    float s = 0.f;
#pragma unroll
    for (int j = 0; j < NCLS; ++j) s += __expf(p[j] - mx);
    float ls = __logf(s);
    if (lane == 0) {
#pragma unroll
        for (int j = 0; j < NCLS; ++j) out[(size_t)node * NCLS + j] = p[j] - mx - ls;
    }
}

extern "C" void kernel_launch(void* const* d_in, const int* in_sizes, int n_in,
                              void* d_out, int out_size, void* d_ws, size_t ws_size,
                              hipStream_t stream) {
    const float* x       = (const float*)d_in[0];
    const float* Wg      = (const float*)d_in[2];
    const float* att_src = (const float*)d_in[3];
    const float* att_dst = (const float*)d_in[4];
    const float* bg      = (const float*)d_in[5];
    const float* Wc      = (const float*)d_in[6];
    const float* bc      = (const float*)d_in[7];
    const float* Wl      = (const float*)d_in[8];
    const float* bl      = (const float*)d_in[9];
    const int*   ei      = (const int*)d_in[10];
    float* out = (float*)d_out;

    char* p = (char*)d_ws;
    auto alloc = [&](size_t bytes) -> void* {
        void* r = (void*)p;
        p += (bytes + 255) & ~(size_t)255;
        return r;
    };
    float* h         = (float*)alloc((size_t)NN * HC * 4);
    float* xg        = (float*)alloc((size_t)NN * HC * 4);
    float* a_s       = (float*)alloc((size_t)NN * 4 * 4);
    float* a_d       = (float*)alloc((size_t)NN * 4 * 4);
    int*   deg       = (int*)alloc((size_t)NN * 4);
    float* dinv      = (float*)alloc((size_t)NN * 4);
    int*   row_start = (int*)alloc((size_t)(NN + 1) * 4);
    int*   cursor    = (int*)alloc((size_t)NN * 4);
    int*   csr_src   = (int*)alloc((size_t)E2 * 4);
    int*   blocksum  = (int*)alloc(256 * 4);
    float* xw = h;             // alias: h dead after gat_kernel
    float* xc = h + (size_t)NN * HID;

    hipMemsetAsync(deg, 0, (size_t)NN * 4, stream);
    hipMemsetAsync(cursor, 0, (size_t)NN * 4, stream);

    gemm32<FIN, HC><<<(NN + 31) / 32, 256, 0, stream>>>(x, Wg, h, NN);
    att_kernel<<<(NN + 3) / 4, 256, 0, stream>>>(h, att_src, att_dst, a_s, a_d);

    deg_kernel<<<(EE + 255) / 256, 256, 0, stream>>>(ei, deg);
    scan_a<<<(NN + 255) / 256, 256, 0, stream>>>(deg, row_start, blocksum);
    scan_b<<<1, 256, 0, stream>>>(blocksum, (NN + 255) / 256);
    scan_c<<<(NN + 255) / 256, 256, 0, stream>>>(row_start, blocksum);
    scatter_kernel<<<(E2 + 255) / 256, 256, 0, stream>>>(ei, row_start, cursor, csr_src);

    gat_kernel<<<(NN + 3) / 4, 256, 0, stream>>>(h, a_s, a_d, row_start, csr_src, bg, xg, dinv);
    gemm32<HC, HID><<<(NN + 31) / 32, 256, 0, stream>>>(xg, Wc, xw, NN);
    gcn_kernel<<<(NN + 3) / 4, 256, 0, stream>>>(xw, row_start, csr_src, dinv, bc, xc);
    head_kernel<<<(NN + 3) / 4, 256, 0, stream>>>(xc, Wl, bl, out);
}

// Round 2
// 451.591 us; speedup vs baseline: 1.2349x; 1.2349x over previous
//
#include <hip/hip_runtime.h>
#include <hip/hip_fp16.h>
#include <math.h>

#define NN 50000
#define EE 800000
#define E2 (EE + NN)
#define FIN 128
#define HC 256
#define HID 128
#define NCLS 10
#define NEG 0.2f

// ---------------- GEMM1 fused: h = x@Wg -> fp16, a_s/a_d dot products in epilogue ----
__global__ __launch_bounds__(256) void gemm1_att(const float* __restrict__ x,
                                                 const float* __restrict__ Wg,
                                                 const float* __restrict__ att_s,
                                                 const float* __restrict__ att_d,
                                                 ushort* __restrict__ h_half,
                                                 float* __restrict__ a_s,
                                                 float* __restrict__ a_d) {
    // K=128, NC=256: CL=64 col-threads (4 cols each), 4 waves, 8 rows/thread
    __shared__ float xs[32][FIN];
    const int row0 = blockIdx.x * 32;
    const int t = threadIdx.x;
    for (int idx = t; idx < 32 * (FIN / 4); idx += 256) {
        int r = idx >> 5, k4 = idx & 31;
        int row = row0 + r;
        float4 v = (row < NN) ? ((const float4*)x)[(size_t)row * (FIN / 4) + k4]
                              : make_float4(0.f, 0.f, 0.f, 0.f);
        ((float4*)&xs[r][0])[k4] = v;
    }
    __syncthreads();
    const int tc = t & 63;   // column group: cols tc*4..tc*4+3
    const int tr = t >> 6;   // wave id: rows tr*8..tr*8+7

    float4 asv = ((const float4*)att_s)[tc];
    float4 adv = ((const float4*)att_d)[tc];

    float acc[8][4];
#pragma unroll
    for (int r = 0; r < 8; ++r) { acc[r][0]=0.f; acc[r][1]=0.f; acc[r][2]=0.f; acc[r][3]=0.f; }

    const float4* Wv = (const float4*)Wg;
    for (int k = 0; k < FIN; k += 4) {
        float4 w0 = Wv[(k + 0) * 64 + tc];
        float4 w1 = Wv[(k + 1) * 64 + tc];
        float4 w2 = Wv[(k + 2) * 64 + tc];
        float4 w3 = Wv[(k + 3) * 64 + tc];
#pragma unroll
        for (int r = 0; r < 8; ++r) {
            float4 xv = *(const float4*)&xs[tr * 8 + r][k];
            acc[r][0] += xv.x * w0.x + xv.y * w1.x + xv.z * w2.x + xv.w * w3.x;
            acc[r][1] += xv.x * w0.y + xv.y * w1.y + xv.z * w2.y + xv.w * w3.y;
            acc[r][2] += xv.x * w0.z + xv.y * w1.z + xv.z * w2.z + xv.w * w3.z;
            acc[r][3] += xv.x * w0.w + xv.y * w1.w + xv.z * w2.w + xv.w * w3.w;
        }
    }
#pragma unroll
    for (int r = 0; r < 8; ++r) {
        int row = row0 + tr * 8 + r;
        if (row >= NN) break;
        // fp16 store of 4 cols
        ushort4 u;
        u.x = __half_as_ushort(__float2half(acc[r][0]));
        u.y = __half_as_ushort(__float2half(acc[r][1]));
        u.z = __half_as_ushort(__float2half(acc[r][2]));
        u.w = __half_as_ushort(__float2half(acc[r][3]));
        ((ushort4*)h_half)[(size_t)row * 64 + tc] = u;
        // attention partials: this thread's 4 cols all belong to head tc/16
        float ps = acc[r][0]*asv.x + acc[r][1]*asv.y + acc[r][2]*asv.z + acc[r][3]*asv.w;
        float pd = acc[r][0]*adv.x + acc[r][1]*adv.y + acc[r][2]*adv.z + acc[r][3]*adv.w;
#pragma unroll
        for (int m = 8; m >= 1; m >>= 1) {
            ps += __shfl_xor(ps, m, 64);
            pd += __shfl_xor(pd, m, 64);
        }
        if ((tc & 15) == 0) {
            a_s[row * 4 + (tc >> 4)] = ps;
            a_d[row * 4 + (tc >> 4)] = pd;
        }
    }
}

// ---------------- GEMM2: xw = xg@Wc -> fp16 ----------------
__global__ __launch_bounds__(256) void gemm2h(const float* __restrict__ A,
                                              const float* __restrict__ W,
                                              ushort* __restrict__ out) {
    // K=256, NC=128: CL=32, 8 row-groups, 4 rows/thread
    __shared__ float xs[32][HC];
    const int row0 = blockIdx.x * 32;
    const int t = threadIdx.x;
    for (int idx = t; idx < 32 * (HC / 4); idx += 256) {
        int r = idx >> 6, k4 = idx & 63;
        int row = row0 + r;
        float4 v = (row < NN) ? ((const float4*)A)[(size_t)row * (HC / 4) + k4]
                              : make_float4(0.f, 0.f, 0.f, 0.f);
        ((float4*)&xs[r][0])[k4] = v;
    }
    __syncthreads();
    const int tc = t & 31;
    const int tr = t >> 5;
    float acc[4][4];
#pragma unroll
    for (int r = 0; r < 4; ++r) { acc[r][0]=0.f; acc[r][1]=0.f; acc[r][2]=0.f; acc[r][3]=0.f; }

    const float4* Wv = (const float4*)W;
    for (int k = 0; k < HC; k += 4) {
        float4 w0 = Wv[(k + 0) * 32 + tc];
        float4 w1 = Wv[(k + 1) * 32 + tc];
        float4 w2 = Wv[(k + 2) * 32 + tc];
        float4 w3 = Wv[(k + 3) * 32 + tc];
#pragma unroll
        for (int r = 0; r < 4; ++r) {
            float4 xv = *(const float4*)&xs[tr * 4 + r][k];
            acc[r][0] += xv.x * w0.x + xv.y * w1.x + xv.z * w2.x + xv.w * w3.x;
            acc[r][1] += xv.x * w0.y + xv.y * w1.y + xv.z * w2.y + xv.w * w3.y;
            acc[r][2] += xv.x * w0.z + xv.y * w1.z + xv.z * w2.z + xv.w * w3.z;
            acc[r][3] += xv.x * w0.w + xv.y * w1.w + xv.z * w2.w + xv.w * w3.w;
        }
    }
#pragma unroll
    for (int r = 0; r < 4; ++r) {
        int row = row0 + tr * 4 + r;
        if (row < NN) {
            ushort4 u;
            u.x = __half_as_ushort(__float2half(acc[r][0]));
            u.y = __half_as_ushort(__float2half(acc[r][1]));
            u.z = __half_as_ushort(__float2half(acc[r][2]));
            u.w = __half_as_ushort(__float2half(acc[r][3]));
            ((ushort4*)out)[(size_t)row * 32 + tc] = u;
        }
    }
}

// ---------------- CSR build ----------------
__global__ __launch_bounds__(256) void deg_kernel(const int* __restrict__ ei, int* __restrict__ deg) {
    int e = blockIdx.x * 256 + threadIdx.x;
    if (e < EE) atomicAdd(&deg[ei[EE + e]], 1);
}

__global__ __launch_bounds__(256) void scan_a(const int* __restrict__ deg, int* __restrict__ row_start,
                                              int* __restrict__ blocksum) {
    __shared__ int sh[256];
    int t = threadIdx.x;
    int i = blockIdx.x * 256 + t;
    int v = (i < NN) ? (deg[i] + 1) : 0;   // +1 self loop
    sh[t] = v;
    __syncthreads();
#pragma unroll
    for (int off = 1; off < 256; off <<= 1) {
        int y = (t >= off) ? sh[t - off] : 0;
        __syncthreads();
        sh[t] += y;
        __syncthreads();
    }
    if (i < NN) row_start[i] = sh[t] - v;
    if (t == 255) blocksum[blockIdx.x] = sh[255];
}

__global__ __launch_bounds__(256) void scan_b(int* __restrict__ bs, int nb) {
    __shared__ int sh[256];
    int t = threadIdx.x;
    int v = (t < nb) ? bs[t] : 0;
    sh[t] = v;
    __syncthreads();
#pragma unroll
    for (int off = 1; off < 256; off <<= 1) {
        int y = (t >= off) ? sh[t - off] : 0;
        __syncthreads();
        sh[t] += y;
        __syncthreads();
    }
    if (t < nb) bs[t] = sh[t] - v;
}

__global__ __launch_bounds__(256) void scan_c(int* __restrict__ row_start, const int* __restrict__ bs) {
    int i = blockIdx.x * 256 + threadIdx.x;
    if (i < NN) row_start[i] += bs[blockIdx.x];
    if (i == 0) row_start[NN] = E2;
}

__global__ __launch_bounds__(256) void scatter_kernel(const int* __restrict__ ei,
                                                      const int* __restrict__ row_start,
                                                      int* __restrict__ cursor,
                                                      int* __restrict__ csr_src) {
    int e = blockIdx.x * 256 + threadIdx.x;
    if (e >= E2) return;
    int src, dst;
    if (e < EE) { src = ei[e]; dst = ei[EE + e]; }
    else        { src = dst = e - EE; }
    int pos = row_start[dst] + atomicAdd(&cursor[dst], 1);
    csr_src[pos] = src;
}

// ---------------- fused GAT: single pass (no max; softmax is shift-invariant) ----------
__global__ __launch_bounds__(256) void gat_half(const ushort* __restrict__ h_half,
                                                const float* __restrict__ a_s,
                                                const float* __restrict__ a_d,
                                                const int* __restrict__ row_start,
                                                const int* __restrict__ csr_src,
                                                const float* __restrict__ bg,
                                                float* __restrict__ xg,
                                                float* __restrict__ dinv) {
    int node = blockIdx.x * 4 + (threadIdx.x >> 6);
    int lane = threadIdx.x & 63;
    if (node >= NN) return;
    int s0 = row_start[node], s1 = row_start[node + 1];
    float4 ad = ((const float4*)a_d)[node];
    bool hi = lane >= 32;

    float den0 = 0.f, den1 = 0.f, den2 = 0.f, den3 = 0.f;
    float a0x = 0.f, a0y = 0.f, a1x = 0.f, a1y = 0.f;
    for (int e = s0; e < s1; ++e) {
        int src = csr_src[e];
        float4 as = ((const float4*)a_s)[src];
        float v0 = as.x + ad.x; v0 = v0 > 0.f ? v0 : NEG * v0;
        float v1 = as.y + ad.y; v1 = v1 > 0.f ? v1 : NEG * v1;
        float v2 = as.z + ad.z; v2 = v2 > 0.f ? v2 : NEG * v2;
        float v3 = as.w + ad.w; v3 = v3 > 0.f ? v3 : NEG * v3;
        float e0 = __expf(v0); den0 += e0;
        float e1 = __expf(v1); den1 += e1;
        float e2 = __expf(v2); den2 += e2;
        float e3 = __expf(v3); den3 += e3;
        // chunk0: cols 2*lane, 2*lane+1 (head = lane<32 ? 0 : 1)
        // chunk1: cols 128+2*lane      (head = lane<32 ? 2 : 3)
        const __half2* hr = (const __half2*)(h_half + (size_t)src * HC);
        float2 hv0 = __half22float2(hr[lane]);
        float2 hv1 = __half22float2(hr[64 + lane]);
        float w0 = hi ? e1 : e0;
        float w1 = hi ? e3 : e2;
        a0x += w0 * hv0.x; a0y += w0 * hv0.y;
        a1x += w1 * hv1.x; a1y += w1 * hv1.y;
    }
    float d0 = hi ? den1 : den0;
    float d1 = hi ? den3 : den2;
    float2 b0 = ((const float2*)bg)[lane];
    float2 b1 = ((const float2*)bg)[64 + lane];
    float o0 = a0x / d0 + b0.x;
    float o1 = a0y / d0 + b0.y;
    float o2 = a1x / d1 + b1.x;
    float o3 = a1y / d1 + b1.y;
    o0 = o0 > 0.f ? o0 : __expf(o0) - 1.f;
    o1 = o1 > 0.f ? o1 : __expf(o1) - 1.f;
    o2 = o2 > 0.f ? o2 : __expf(o2) - 1.f;
    o3 = o3 > 0.f ? o3 : __expf(o3) - 1.f;
    float* xr = xg + (size_t)node * HC;
    ((float2*)xr)[lane]      = make_float2(o0, o1);
    ((float2*)xr)[64 + lane] = make_float2(o2, o3);
    if (lane == 0) dinv[node] = rsqrtf((float)(s1 - s0));
}

// ---------------- GCN: xc = relu(sym-norm SpMM(xw_fp16) + bc) ----------------
__global__ __launch_bounds__(256) void gcn_half(const ushort* __restrict__ xw_half,
                                                const int* __restrict__ row_start,
                                                const int* __restrict__ csr_src,
                                                const float* __restrict__ dinv,
                                                const float* __restrict__ bc,
                                                float* __restrict__ xc) {
    int node = blockIdx.x * 4 + (threadIdx.x >> 6);
    int lane = threadIdx.x & 63;
    if (node >= NN) return;
    int s0 = row_start[node], s1 = row_start[node + 1];
    float di = dinv[node];
    float ax = 0.f, ay = 0.f;
    for (int e = s0; e < s1; ++e) {
        int src = csr_src[e];
        float w = dinv[src] * di;
        float2 v = __half22float2(((const __half2*)(xw_half + (size_t)src * HID))[lane]);
        ax += w * v.x; ay += w * v.y;
    }
    float2 b = ((const float2*)bc)[lane];
    float o0 = ax + b.x, o1 = ay + b.y;
    ((float2*)(xc + (size_t)node * HID))[lane] =
        make_float2(o0 > 0.f ? o0 : 0.f, o1 > 0.f ? o1 : 0.f);
}

// ---------------- classifier + log_softmax ----------------
__global__ __launch_bounds__(256) void head_kernel(const float* __restrict__ xc,
                                                   const float* __restrict__ Wl,
                                                   const float* __restrict__ bl,
                                                   float* __restrict__ out) {
    int node = blockIdx.x * 4 + (threadIdx.x >> 6);
    int lane = threadIdx.x & 63;
    if (node >= NN) return;
    float x0 = xc[(size_t)node * HID + lane];
    float x1 = xc[(size_t)node * HID + 64 + lane];
    float p[NCLS];
#pragma unroll
    for (int j = 0; j < NCLS; ++j)
        p[j] = x0 * Wl[lane * NCLS + j] + x1 * Wl[(64 + lane) * NCLS + j];
#pragma unroll
    for (int m = 32; m >= 1; m >>= 1) {
#pragma unroll
        for (int j = 0; j < NCLS; ++j) p[j] += __shfl_xor(p[j], m, 64);
    }
#pragma unroll
    for (int j = 0; j < NCLS; ++j) p[j] += bl[j];
    float mx = p[0];
#pragma unroll
    for (int j = 1; j < NCLS; ++j) mx = fmaxf(mx, p[j]);
    float s = 0.f;
#pragma unroll
    for (int j = 0; j < NCLS; ++j) s += __expf(p[j] - mx);
    float ls = __logf(s);
    if (lane == 0) {
#pragma unroll
        for (int j = 0; j < NCLS; ++j) out[(size_t)node * NCLS + j] = p[j] - mx - ls;
    }
}

extern "C" void kernel_launch(void* const* d_in, const int* in_sizes, int n_in,
                              void* d_out, int out_size, void* d_ws, size_t ws_size,
                              hipStream_t stream) {
    const float* x       = (const float*)d_in[0];
    const float* Wg      = (const float*)d_in[2];
    const float* att_src = (const float*)d_in[3];
    const float* att_dst = (const float*)d_in[4];
    const float* bg      = (const float*)d_in[5];
    const float* Wc      = (const float*)d_in[6];
    const float* bc      = (const float*)d_in[7];
    const float* Wl      = (const float*)d_in[8];
    const float* bl      = (const float*)d_in[9];
    const int*   ei      = (const int*)d_in[10];
    float* out = (float*)d_out;

    char* p = (char*)d_ws;
    auto alloc = [&](size_t bytes) -> void* {
        void* r = (void*)p;
        p += (bytes + 255) & ~(size_t)255;
        return r;
    };
    ushort* h_half    = (ushort*)alloc((size_t)NN * HC * 2);
    ushort* xw_half   = (ushort*)alloc((size_t)NN * HID * 2);
    float*  xg        = (float*)alloc((size_t)NN * HC * 4);
    float*  xc        = (float*)alloc((size_t)NN * HID * 4);
    float*  a_s       = (float*)alloc((size_t)NN * 4 * 4);
    float*  a_d       = (float*)alloc((size_t)NN * 4 * 4);
    int*    deg       = (int*)alloc((size_t)NN * 4);
    float*  dinv      = (float*)alloc((size_t)NN * 4);
    int*    row_start = (int*)alloc((size_t)(NN + 1) * 4);
    int*    cursor    = (int*)alloc((size_t)NN * 4);
    int*    csr_src   = (int*)alloc((size_t)E2 * 4);
    int*    blocksum  = (int*)alloc(256 * 4);

    hipMemsetAsync(deg, 0, (size_t)NN * 4, stream);
    hipMemsetAsync(cursor, 0, (size_t)NN * 4, stream);

    gemm1_att<<<(NN + 31) / 32, 256, 0, stream>>>(x, Wg, att_src, att_dst, h_half, a_s, a_d);

    deg_kernel<<<(EE + 255) / 256, 256, 0, stream>>>(ei, deg);
    scan_a<<<(NN + 255) / 256, 256, 0, stream>>>(deg, row_start, blocksum);
    scan_b<<<1, 256, 0, stream>>>(blocksum, (NN + 255) / 256);
    scan_c<<<(NN + 255) / 256, 256, 0, stream>>>(row_start, blocksum);
    scatter_kernel<<<(E2 + 255) / 256, 256, 0, stream>>>(ei, row_start, cursor, csr_src);

    gat_half<<<(NN + 3) / 4, 256, 0, stream>>>(h_half, a_s, a_d, row_start, csr_src, bg, xg, dinv);
    gemm2h<<<(NN + 31) / 32, 256, 0, stream>>>(xg, Wc, xw_half);
    gcn_half<<<(NN + 3) / 4, 256, 0, stream>>>(xw_half, row_start, csr_src, dinv, bc, xc);
    head_kernel<<<(NN + 3) / 4, 256, 0, stream>>>(xc, Wl, bl, out);
}

// Round 3
// 361.533 us; speedup vs baseline: 1.5425x; 1.2491x over previous
//
#include <hip/hip_runtime.h>
#include <hip/hip_fp16.h>
#include <math.h>

#define NN 50000
#define EE 800000
#define E2 (EE + NN)
#define FIN 128
#define HC 256
#define HID 128
#define NCLS 10
#define NEG 0.2f

// ---------------- GEMM1 fused: h = x@Wg -> fp16 (interleaved), a_s/a_d in epilogue ----
// h layout: per row, ushort4 slot l (l=0..63) = {col 2l, col 2l+1, col 128+2l, col 129+2l}
__global__ __launch_bounds__(256) void gemm1_att(const float* __restrict__ x,
                                                 const float* __restrict__ Wg,
                                                 const float* __restrict__ att_s,
                                                 const float* __restrict__ att_d,
                                                 ushort* __restrict__ h_half,
                                                 float* __restrict__ a_s,
                                                 float* __restrict__ a_d) {
    __shared__ float xs[32][FIN];
    const int row0 = blockIdx.x * 32;
    const int t = threadIdx.x;
    for (int idx = t; idx < 32 * (FIN / 4); idx += 256) {
        int r = idx >> 5, k4 = idx & 31;
        int row = row0 + r;
        float4 v = (row < NN) ? ((const float4*)x)[(size_t)row * (FIN / 4) + k4]
                              : make_float4(0.f, 0.f, 0.f, 0.f);
        ((float4*)&xs[r][0])[k4] = v;
    }
    __syncthreads();
    const int tc = t & 63;   // cols 4tc..4tc+3
    const int tr = t >> 6;

    float4 asv = ((const float4*)att_s)[tc];
    float4 adv = ((const float4*)att_d)[tc];

    float acc[8][4];
#pragma unroll
    for (int r = 0; r < 8; ++r) { acc[r][0]=0.f; acc[r][1]=0.f; acc[r][2]=0.f; acc[r][3]=0.f; }

    const float4* Wv = (const float4*)Wg;
    for (int k = 0; k < FIN; k += 4) {
        float4 w0 = Wv[(k + 0) * 64 + tc];
        float4 w1 = Wv[(k + 1) * 64 + tc];
        float4 w2 = Wv[(k + 2) * 64 + tc];
        float4 w3 = Wv[(k + 3) * 64 + tc];
#pragma unroll
        for (int r = 0; r < 8; ++r) {
            float4 xv = *(const float4*)&xs[tr * 8 + r][k];
            acc[r][0] += xv.x * w0.x + xv.y * w1.x + xv.z * w2.x + xv.w * w3.x;
            acc[r][1] += xv.x * w0.y + xv.y * w1.y + xv.z * w2.y + xv.w * w3.y;
            acc[r][2] += xv.x * w0.z + xv.y * w1.z + xv.z * w2.z + xv.w * w3.z;
            acc[r][3] += xv.x * w0.w + xv.y * w1.w + xv.z * w2.w + xv.w * w3.w;
        }
    }
    const int l0 = (tc & 31) * 2;          // ushort4 slot of first pair
    const int off = (tc < 32) ? 0 : 1;     // low half (cols<128) or high half
#pragma unroll
    for (int r = 0; r < 8; ++r) {
        int row = row0 + tr * 8 + r;
        if (row >= NN) break;
        ushort2 u01, u23;
        u01.x = __half_as_ushort(__float2half(acc[r][0]));
        u01.y = __half_as_ushort(__float2half(acc[r][1]));
        u23.x = __half_as_ushort(__float2half(acc[r][2]));
        u23.y = __half_as_ushort(__float2half(acc[r][3]));
        ((ushort2*)h_half)[((size_t)row * 64 + l0) * 2 + off]     = u01;
        ((ushort2*)h_half)[((size_t)row * 64 + l0 + 1) * 2 + off] = u23;
        float ps = acc[r][0]*asv.x + acc[r][1]*asv.y + acc[r][2]*asv.z + acc[r][3]*asv.w;
        float pd = acc[r][0]*adv.x + acc[r][1]*adv.y + acc[r][2]*adv.z + acc[r][3]*adv.w;
#pragma unroll
        for (int m = 8; m >= 1; m >>= 1) {
            ps += __shfl_xor(ps, m, 64);
            pd += __shfl_xor(pd, m, 64);
        }
        if ((tc & 15) == 0) {
            a_s[row * 4 + (tc >> 4)] = ps;
            a_d[row * 4 + (tc >> 4)] = pd;
        }
    }
}

// ---------------- GEMM2: xw = xg(fp16)@Wc -> fp16 ----------------
__global__ __launch_bounds__(256) void gemm2h(const ushort* __restrict__ A,
                                              const float* __restrict__ W,
                                              ushort* __restrict__ out) {
    __shared__ float xs[32][HC];
    const int row0 = blockIdx.x * 32;
    const int t = threadIdx.x;
    for (int idx = t; idx < 32 * 64; idx += 256) {
        int r = idx >> 6, c4 = idx & 63;
        int row = row0 + r;
        float4 f = make_float4(0.f, 0.f, 0.f, 0.f);
        if (row < NN) {
            ushort4 u = ((const ushort4*)A)[(size_t)row * 64 + c4];
            f.x = __half2float(__ushort_as_half(u.x));
            f.y = __half2float(__ushort_as_half(u.y));
            f.z = __half2float(__ushort_as_half(u.z));
            f.w = __half2float(__ushort_as_half(u.w));
        }
        ((float4*)&xs[r][0])[c4] = f;
    }
    __syncthreads();
    const int tc = t & 31;
    const int tr = t >> 5;
    float acc[4][4];
#pragma unroll
    for (int r = 0; r < 4; ++r) { acc[r][0]=0.f; acc[r][1]=0.f; acc[r][2]=0.f; acc[r][3]=0.f; }

    const float4* Wv = (const float4*)W;
    for (int k = 0; k < HC; k += 4) {
        float4 w0 = Wv[(k + 0) * 32 + tc];
        float4 w1 = Wv[(k + 1) * 32 + tc];
        float4 w2 = Wv[(k + 2) * 32 + tc];
        float4 w3 = Wv[(k + 3) * 32 + tc];
#pragma unroll
        for (int r = 0; r < 4; ++r) {
            float4 xv = *(const float4*)&xs[tr * 4 + r][k];
            acc[r][0] += xv.x * w0.x + xv.y * w1.x + xv.z * w2.x + xv.w * w3.x;
            acc[r][1] += xv.x * w0.y + xv.y * w1.y + xv.z * w2.y + xv.w * w3.y;
            acc[r][2] += xv.x * w0.z + xv.y * w1.z + xv.z * w2.z + xv.w * w3.z;
            acc[r][3] += xv.x * w0.w + xv.y * w1.w + xv.z * w2.w + xv.w * w3.w;
        }
    }
#pragma unroll
    for (int r = 0; r < 4; ++r) {
        int row = row0 + tr * 4 + r;
        if (row < NN) {
            ushort4 u;
            u.x = __half_as_ushort(__float2half(acc[r][0]));
            u.y = __half_as_ushort(__float2half(acc[r][1]));
            u.z = __half_as_ushort(__float2half(acc[r][2]));
            u.w = __half_as_ushort(__float2half(acc[r][3]));
            ((ushort4*)out)[(size_t)row * 32 + tc] = u;
        }
    }
}

// ---------------- CSR build ----------------
__global__ __launch_bounds__(256) void deg_kernel(const int* __restrict__ ei, int* __restrict__ deg) {
    int e = blockIdx.x * 256 + threadIdx.x;
    if (e < EE) atomicAdd(&deg[ei[EE + e]], 1);
}

__global__ __launch_bounds__(256) void scan_a(const int* __restrict__ deg, int* __restrict__ row_start,
                                              int* __restrict__ blocksum) {
    __shared__ int sh[256];
    int t = threadIdx.x;
    int i = blockIdx.x * 256 + t;
    int v = (i < NN) ? (deg[i] + 1) : 0;
    sh[t] = v;
    __syncthreads();
#pragma unroll
    for (int off = 1; off < 256; off <<= 1) {
        int y = (t >= off) ? sh[t - off] : 0;
        __syncthreads();
        sh[t] += y;
        __syncthreads();
    }
    if (i < NN) row_start[i] = sh[t] - v;
    if (t == 255) blocksum[blockIdx.x] = sh[255];
}

__global__ __launch_bounds__(256) void scan_b(int* __restrict__ bs, int nb) {
    __shared__ int sh[256];
    int t = threadIdx.x;
    int v = (t < nb) ? bs[t] : 0;
    sh[t] = v;
    __syncthreads();
#pragma unroll
    for (int off = 1; off < 256; off <<= 1) {
        int y = (t >= off) ? sh[t - off] : 0;
        __syncthreads();
        sh[t] += y;
        __syncthreads();
    }
    if (t < nb) bs[t] = sh[t] - v;
}

__global__ __launch_bounds__(256) void scan_c(int* __restrict__ row_start, const int* __restrict__ bs) {
    int i = blockIdx.x * 256 + threadIdx.x;
    if (i < NN) row_start[i] += bs[blockIdx.x];
    if (i == 0) row_start[NN] = E2;
}

__global__ __launch_bounds__(256) void scatter_kernel(const int* __restrict__ ei,
                                                      const int* __restrict__ row_start,
                                                      int* __restrict__ cursor,
                                                      int* __restrict__ csr_src) {
    int e = blockIdx.x * 256 + threadIdx.x;
    if (e >= E2) return;
    int src, dst;
    if (e < EE) { src = ei[e]; dst = ei[EE + e]; }
    else        { src = dst = e - EE; }
    int pos = row_start[dst] + atomicAdd(&cursor[dst], 1);
    csr_src[pos] = src;
}

// ---------------- fused GAT, wave-cooperative two-phase ----------------
__global__ __launch_bounds__(256) void gat_half(const ushort* __restrict__ h_half,
                                                const float* __restrict__ a_s,
                                                const float* __restrict__ a_d,
                                                const int* __restrict__ row_start,
                                                const int* __restrict__ csr_src,
                                                const float* __restrict__ bg,
                                                ushort* __restrict__ xg,
                                                float* __restrict__ dinv) {
    __shared__ int   lds_src[4][64];
    __shared__ float4 lds_ex[4][64];
    const int wid  = threadIdx.x >> 6;
    const int lane = threadIdx.x & 63;
    const int node = blockIdx.x * 4 + wid;
    if (node >= NN) return;
    const int s0 = row_start[node], s1 = row_start[node + 1];
    const float4 ad = ((const float4*)a_d)[node];
    const bool hi = lane >= 32;

    float den0 = 0.f, den1 = 0.f, den2 = 0.f, den3 = 0.f;
    float a0x = 0.f, a0y = 0.f, a1x = 0.f, a1y = 0.f;
    const ushort4* hv4 = (const ushort4*)h_half;

    for (int e = s0; e < s1; e += 64) {
        const int m = min(64, s1 - e);
        if (lane < m) {
            int src = csr_src[e + lane];
            float4 as = ((const float4*)a_s)[src];
            float v0 = as.x + ad.x; v0 = v0 > 0.f ? v0 : NEG * v0;
            float v1 = as.y + ad.y; v1 = v1 > 0.f ? v1 : NEG * v1;
            float v2 = as.z + ad.z; v2 = v2 > 0.f ? v2 : NEG * v2;
            float v3 = as.w + ad.w; v3 = v3 > 0.f ? v3 : NEG * v3;
            float e0 = __expf(v0); den0 += e0;
            float e1 = __expf(v1); den1 += e1;
            float e2 = __expf(v2); den2 += e2;
            float e3 = __expf(v3); den3 += e3;
            lds_src[wid][lane] = src;
            lds_ex[wid][lane]  = make_float4(e0, e2, e1, e3);  // lo lanes read .xy, hi read .zw
        }
        asm volatile("" ::: "memory");
#pragma unroll 2
        for (int j = 0; j < m; ++j) {
            int s = lds_src[wid][j];
            float4 ex = lds_ex[wid][j];
            float w0 = hi ? ex.z : ex.x;
            float w1 = hi ? ex.w : ex.y;
            ushort4 u = hv4[(size_t)s * 64 + lane];
            a0x += w0 * __half2float(__ushort_as_half(u.x));
            a0y += w0 * __half2float(__ushort_as_half(u.y));
            a1x += w1 * __half2float(__ushort_as_half(u.z));
            a1y += w1 * __half2float(__ushort_as_half(u.w));
        }
        asm volatile("" ::: "memory");
    }
#pragma unroll
    for (int m = 32; m >= 1; m >>= 1) {
        den0 += __shfl_xor(den0, m, 64);
        den1 += __shfl_xor(den1, m, 64);
        den2 += __shfl_xor(den2, m, 64);
        den3 += __shfl_xor(den3, m, 64);
    }
    float d0 = hi ? den1 : den0;
    float d1 = hi ? den3 : den2;
    float2 b0 = ((const float2*)bg)[lane];
    float2 b1 = ((const float2*)bg)[64 + lane];
    float o0 = a0x / d0 + b0.x;
    float o1 = a0y / d0 + b0.y;
    float o2 = a1x / d1 + b1.x;
    float o3 = a1y / d1 + b1.y;
    o0 = o0 > 0.f ? o0 : __expf(o0) - 1.f;
    o1 = o1 > 0.f ? o1 : __expf(o1) - 1.f;
    o2 = o2 > 0.f ? o2 : __expf(o2) - 1.f;
    o3 = o3 > 0.f ? o3 : __expf(o3) - 1.f;
    ushort2 w01, w23;
    w01.x = __half_as_ushort(__float2half(o0));
    w01.y = __half_as_ushort(__float2half(o1));
    w23.x = __half_as_ushort(__float2half(o2));
    w23.y = __half_as_ushort(__float2half(o3));
    ((ushort2*)xg)[(size_t)node * 128 + lane]      = w01;  // cols 2l,2l+1
    ((ushort2*)xg)[(size_t)node * 128 + 64 + lane] = w23;  // cols 128+2l,129+2l
    if (lane == 0) dinv[node] = rsqrtf((float)(s1 - s0));
}

// ---------------- GCN, wave-cooperative two-phase ----------------
__global__ __launch_bounds__(256) void gcn_half(const ushort* __restrict__ xw_half,
                                                const int* __restrict__ row_start,
                                                const int* __restrict__ csr_src,
                                                const float* __restrict__ dinv,
                                                const float* __restrict__ bc,
                                                float* __restrict__ xc) {
    __shared__ int   lds_src[4][64];
    __shared__ float lds_w[4][64];
    const int wid  = threadIdx.x >> 6;
    const int lane = threadIdx.x & 63;
    const int node = blockIdx.x * 4 + wid;
    if (node >= NN) return;
    const int s0 = row_start[node], s1 = row_start[node + 1];
    const float di = dinv[node];
    float ax = 0.f, ay = 0.f;
    const __half2* xw2 = (const __half2*)xw_half;

    for (int e = s0; e < s1; e += 64) {
        const int m = min(64, s1 - e);
        if (lane < m) {
            int s = csr_src[e + lane];
            lds_src[wid][lane] = s;
            lds_w[wid][lane]   = dinv[s] * di;
        }
        asm volatile("" ::: "memory");
#pragma unroll 2
        for (int j = 0; j < m; ++j) {
            int s = lds_src[wid][j];
            float w = lds_w[wid][j];
            float2 v = __half22float2(xw2[(size_t)s * 64 + lane]);
            ax += w * v.x; ay += w * v.y;
        }
        asm volatile("" ::: "memory");
    }
    float2 b = ((const float2*)bc)[lane];
    float o0 = ax + b.x, o1 = ay + b.y;
    ((float2*)(xc + (size_t)node * HID))[lane] =
        make_float2(o0 > 0.f ? o0 : 0.f, o1 > 0.f ? o1 : 0.f);
}

// ---------------- classifier + log_softmax ----------------
__global__ __launch_bounds__(256) void head_kernel(const float* __restrict__ xc,
                                                   const float* __restrict__ Wl,
                                                   const float* __restrict__ bl,
                                                   float* __restrict__ out) {
    int node = blockIdx.x * 4 + (threadIdx.x >> 6);
    int lane = threadIdx.x & 63;
    if (node >= NN) return;
    float x0 = xc[(size_t)node * HID + lane];
    float x1 = xc[(size_t)node * HID + 64 + lane];
    float p[NCLS];
#pragma unroll
    for (int j = 0; j < NCLS; ++j)
        p[j] = x0 * Wl[lane * NCLS + j] + x1 * Wl[(64 + lane) * NCLS + j];
#pragma unroll
    for (int m = 32; m >= 1; m >>= 1) {
#pragma unroll
        for (int j = 0; j < NCLS; ++j) p[j] += __shfl_xor(p[j], m, 64);
    }
#pragma unroll
    for (int j = 0; j < NCLS; ++j) p[j] += bl[j];
    float mx = p[0];
#pragma unroll
    for (int j = 1; j < NCLS; ++j) mx = fmaxf(mx, p[j]);
    float s = 0.f;
#pragma unroll
    for (int j = 0; j < NCLS; ++j) s += __expf(p[j] - mx);
    float ls = __logf(s);
    if (lane == 0) {
#pragma unroll
        for (int j = 0; j < NCLS; ++j) out[(size_t)node * NCLS + j] = p[j] - mx - ls;
    }
}

extern "C" void kernel_launch(void* const* d_in, const int* in_sizes, int n_in,
                              void* d_out, int out_size, void* d_ws, size_t ws_size,
                              hipStream_t stream) {
    const float* x       = (const float*)d_in[0];
    const float* Wg      = (const float*)d_in[2];
    const float* att_src = (const float*)d_in[3];
    const float* att_dst = (const float*)d_in[4];
    const float* bg      = (const float*)d_in[5];
    const float* Wc      = (const float*)d_in[6];
    const float* bc      = (const float*)d_in[7];
    const float* Wl      = (const float*)d_in[8];
    const float* bl      = (const float*)d_in[9];
    const int*   ei      = (const int*)d_in[10];
    float* out = (float*)d_out;

    char* p = (char*)d_ws;
    auto alloc = [&](size_t bytes) -> void* {
        void* r = (void*)p;
        p += (bytes + 255) & ~(size_t)255;
        return r;
    };
    ushort* h_half    = (ushort*)alloc((size_t)NN * HC * 2);
    ushort* xg_half   = (ushort*)alloc((size_t)NN * HC * 2);
    ushort* xw_half   = (ushort*)alloc((size_t)NN * HID * 2);
    float*  xc        = (float*)alloc((size_t)NN * HID * 4);
    float*  a_s       = (float*)alloc((size_t)NN * 4 * 4);
    float*  a_d       = (float*)alloc((size_t)NN * 4 * 4);
    int*    deg       = (int*)alloc((size_t)NN * 4);
    float*  dinv      = (float*)alloc((size_t)NN * 4);
    int*    row_start = (int*)alloc((size_t)(NN + 1) * 4);
    int*    cursor    = (int*)alloc((size_t)NN * 4);
    int*    csr_src   = (int*)alloc((size_t)E2 * 4);
    int*    blocksum  = (int*)alloc(256 * 4);

    hipMemsetAsync(deg, 0, (size_t)NN * 4, stream);
    hipMemsetAsync(cursor, 0, (size_t)NN * 4, stream);

    gemm1_att<<<(NN + 31) / 32, 256, 0, stream>>>(x, Wg, att_src, att_dst, h_half, a_s, a_d);

    deg_kernel<<<(EE + 255) / 256, 256, 0, stream>>>(ei, deg);
    scan_a<<<(NN + 255) / 256, 256, 0, stream>>>(deg, row_start, blocksum);
    scan_b<<<1, 256, 0, stream>>>(blocksum, (NN + 255) / 256);
    scan_c<<<(NN + 255) / 256, 256, 0, stream>>>(row_start, blocksum);
    scatter_kernel<<<(E2 + 255) / 256, 256, 0, stream>>>(ei, row_start, cursor, csr_src);

    gat_half<<<(NN + 3) / 4, 256, 0, stream>>>(h_half, a_s, a_d, row_start, csr_src, bg, xg_half, dinv);
    gemm2h<<<(NN + 31) / 32, 256, 0, stream>>>(xg_half, Wc, xw_half);
    gcn_half<<<(NN + 3) / 4, 256, 0, stream>>>(xw_half, row_start, csr_src, dinv, bc, xc);
    head_kernel<<<(NN + 3) / 4, 256, 0, stream>>>(xc, Wl, bl, out);
}

// Round 4
// 295.130 us; speedup vs baseline: 1.8896x; 1.2250x over previous
//
#include <hip/hip_runtime.h>
#include <hip/hip_fp16.h>
#include <math.h>

#define NN 50000
#define EE 800000
#define E2 (EE + NN)
#define FIN 128
#define HC 256
#define HID 128
#define NCLS 10
#define NEG 0.2f

typedef _Float16 f16x8 __attribute__((ext_vector_type(8)));
typedef float f32x4 __attribute__((ext_vector_type(4)));

__device__ inline f16x8 cvt8(float4 a, float4 b) {
    f16x8 r;
    r[0] = (_Float16)a.x; r[1] = (_Float16)a.y; r[2] = (_Float16)a.z; r[3] = (_Float16)a.w;
    r[4] = (_Float16)b.x; r[5] = (_Float16)b.y; r[6] = (_Float16)b.z; r[7] = (_Float16)b.w;
    return r;
}

// ---------------- prep: WgT_h[256][128], WcT_h[128][256] (fp16, transposed) ----------------
__global__ __launch_bounds__(384) void prep_kernel(const float* __restrict__ Wg,
                                                   const float* __restrict__ Wc,
                                                   ushort* __restrict__ wgt,
                                                   ushort* __restrict__ wct) {
    int t = threadIdx.x;
    if (t < 256) {
        for (int k = 0; k < FIN; ++k)
            wgt[t * FIN + k] = __half_as_ushort(__float2half(Wg[k * HC + t]));
    } else {
        int c = t - 256;
        for (int k = 0; k < HC; ++k)
            wct[c * HC + k] = __half_as_ushort(__float2half(Wc[k * HID + c]));
    }
}

// ---------------- GEMM1 (MFMA): h = x@Wg -> fp16 linear, a_s/a_d in epilogue ----------------
// wave w owns cols [64w, 64w+64) == head w. 3125 row-tiles of 16.
__global__ __launch_bounds__(256) void gemm1_mfma(const float* __restrict__ x,
                                                  const ushort* __restrict__ wgt,
                                                  const float* __restrict__ att_s,
                                                  const float* __restrict__ att_d,
                                                  ushort* __restrict__ h_half,
                                                  float* __restrict__ a_s,
                                                  float* __restrict__ a_d) {
    const int t = threadIdx.x;
    const int w  = t >> 6;
    const int l  = t & 63;
    const int lr = l & 15;   // row-in-tile (A) / col-in-tile (B,D)
    const int lg = l >> 4;   // k-group

    // hoist B fragments: bf[ct][ks], col = 64w+16ct+lr, k = 32ks+8lg+j
    f16x8 bf[4][4];
#pragma unroll
    for (int ct = 0; ct < 4; ++ct)
#pragma unroll
        for (int ks = 0; ks < 4; ++ks)
            bf[ct][ks] = *(const f16x8*)(wgt + (size_t)(64 * w + 16 * ct + lr) * FIN + ks * 32 + 8 * lg);

    float asv[4], adv[4];
#pragma unroll
    for (int ct = 0; ct < 4; ++ct) {
        asv[ct] = att_s[w * 64 + 16 * ct + lr];
        adv[ct] = att_d[w * 64 + 16 * ct + lr];
    }

    for (int rt = blockIdx.x; rt < 3125; rt += gridDim.x) {
        const int r0 = rt * 16;
        f32x4 acc[4];
#pragma unroll
        for (int ct = 0; ct < 4; ++ct) acc[ct] = (f32x4){0.f, 0.f, 0.f, 0.f};

#pragma unroll
        for (int ks = 0; ks < 4; ++ks) {
            const float4* xp = (const float4*)(x + (size_t)(r0 + lr) * FIN + ks * 32 + 8 * lg);
            f16x8 af = cvt8(xp[0], xp[1]);
#pragma unroll
            for (int ct = 0; ct < 4; ++ct)
                acc[ct] = __builtin_amdgcn_mfma_f32_16x16x32_f16(af, bf[ct][ks], acc[ct], 0, 0, 0);
        }
        // D[row = r0+4lg+j][col = 64w+16ct+lr] = acc[ct][j]
#pragma unroll
        for (int j = 0; j < 4; ++j) {
            const int row = r0 + 4 * lg + j;
#pragma unroll
            for (int ct = 0; ct < 4; ++ct)
                h_half[(size_t)row * HC + 64 * w + 16 * ct + lr] =
                    __half_as_ushort(__float2half(acc[ct][j]));
            float ps = 0.f, pd = 0.f;
#pragma unroll
            for (int ct = 0; ct < 4; ++ct) {
                ps += acc[ct][j] * asv[ct];
                pd += acc[ct][j] * adv[ct];
            }
#pragma unroll
            for (int m = 8; m >= 1; m >>= 1) {
                ps += __shfl_xor(ps, m, 64);
                pd += __shfl_xor(pd, m, 64);
            }
            if (lr == 0) {
                a_s[row * 4 + w] = ps;
                a_d[row * 4 + w] = pd;
            }
        }
    }
}

// ---------------- GEMM2 (MFMA): xw = xg(fp16)@Wc -> fp16 linear ----------------
// wave w owns cols [32w, 32w+32). K=256 (8 k-steps).
__global__ __launch_bounds__(256) void gemm2_mfma(const ushort* __restrict__ xg,
                                                  const ushort* __restrict__ wct,
                                                  ushort* __restrict__ xw) {
    const int t = threadIdx.x;
    const int w  = t >> 6;
    const int l  = t & 63;
    const int lr = l & 15;
    const int lg = l >> 4;

    f16x8 bf[2][8];
#pragma unroll
    for (int ct = 0; ct < 2; ++ct)
#pragma unroll
        for (int ks = 0; ks < 8; ++ks)
            bf[ct][ks] = *(const f16x8*)(wct + (size_t)(32 * w + 16 * ct + lr) * HC + ks * 32 + 8 * lg);

    for (int rt = blockIdx.x; rt < 3125; rt += gridDim.x) {
        const int r0 = rt * 16;
        f32x4 acc[2];
        acc[0] = (f32x4){0.f, 0.f, 0.f, 0.f};
        acc[1] = (f32x4){0.f, 0.f, 0.f, 0.f};
#pragma unroll
        for (int ks = 0; ks < 8; ++ks) {
            f16x8 af = *(const f16x8*)(xg + (size_t)(r0 + lr) * HC + ks * 32 + 8 * lg);
            acc[0] = __builtin_amdgcn_mfma_f32_16x16x32_f16(af, bf[0][ks], acc[0], 0, 0, 0);
            acc[1] = __builtin_amdgcn_mfma_f32_16x16x32_f16(af, bf[1][ks], acc[1], 0, 0, 0);
        }
#pragma unroll
        for (int j = 0; j < 4; ++j) {
            const int row = r0 + 4 * lg + j;
#pragma unroll
            for (int ct = 0; ct < 2; ++ct)
                xw[(size_t)row * HID + 32 * w + 16 * ct + lr] =
                    __half_as_ushort(__float2half(acc[ct][j]));
        }
    }
}

// ---------------- CSR build ----------------
__global__ __launch_bounds__(256) void deg_kernel(const int* __restrict__ ei, int* __restrict__ deg) {
    int e = blockIdx.x * 256 + threadIdx.x;
    if (e < EE) atomicAdd(&deg[ei[EE + e]], 1);
}

__global__ __launch_bounds__(256) void scan_a(const int* __restrict__ deg, int* __restrict__ row_start,
                                              int* __restrict__ blocksum) {
    __shared__ int sh[256];
    int t = threadIdx.x;
    int i = blockIdx.x * 256 + t;
    int v = (i < NN) ? (deg[i] + 1) : 0;
    sh[t] = v;
    __syncthreads();
#pragma unroll
    for (int off = 1; off < 256; off <<= 1) {
        int y = (t >= off) ? sh[t - off] : 0;
        __syncthreads();
        sh[t] += y;
        __syncthreads();
    }
    if (i < NN) row_start[i] = sh[t] - v;
    if (t == 255) blocksum[blockIdx.x] = sh[255];
}

__global__ __launch_bounds__(256) void scan_b(int* __restrict__ bs, int nb) {
    __shared__ int sh[256];
    int t = threadIdx.x;
    int v = (t < nb) ? bs[t] : 0;
    sh[t] = v;
    __syncthreads();
#pragma unroll
    for (int off = 1; off < 256; off <<= 1) {
        int y = (t >= off) ? sh[t - off] : 0;
        __syncthreads();
        sh[t] += y;
        __syncthreads();
    }
    if (t < nb) bs[t] = sh[t] - v;
}

__global__ __launch_bounds__(256) void scan_c(int* __restrict__ row_start, const int* __restrict__ bs) {
    int i = blockIdx.x * 256 + threadIdx.x;
    if (i < NN) row_start[i] += bs[blockIdx.x];
    if (i == 0) row_start[NN] = E2;
}

__global__ __launch_bounds__(256) void scatter_kernel(const int* __restrict__ ei,
                                                      const int* __restrict__ row_start,
                                                      int* __restrict__ cursor,
                                                      int* __restrict__ csr_src) {
    int e = blockIdx.x * 256 + threadIdx.x;
    if (e >= E2) return;
    int src, dst;
    if (e < EE) { src = ei[e]; dst = ei[EE + e]; }
    else        { src = dst = e - EE; }
    int pos = row_start[dst] + atomicAdd(&cursor[dst], 1);
    csr_src[pos] = src;
}

// ---------------- fused GAT, wave-cooperative two-phase (linear h) ----------------
__global__ __launch_bounds__(256) void gat_half(const ushort* __restrict__ h_half,
                                                const float* __restrict__ a_s,
                                                const float* __restrict__ a_d,
                                                const int* __restrict__ row_start,
                                                const int* __restrict__ csr_src,
                                                const float* __restrict__ bg,
                                                ushort* __restrict__ xg,
                                                float* __restrict__ dinv) {
    __shared__ int    lds_src[4][64];
    __shared__ float4 lds_ex[4][64];
    const int wid  = threadIdx.x >> 6;
    const int lane = threadIdx.x & 63;
    const int node = blockIdx.x * 4 + wid;
    if (node >= NN) return;
    const int s0 = row_start[node], s1 = row_start[node + 1];
    const float4 ad = ((const float4*)a_d)[node];
    const int comp = lane >> 4;   // which head's weight this lane consumes (cols 4l..4l+3)

    float den0 = 0.f, den1 = 0.f, den2 = 0.f, den3 = 0.f;
    float a0 = 0.f, a1 = 0.f, a2 = 0.f, a3 = 0.f;
    const ushort4* hv4 = (const ushort4*)h_half;

    for (int e = s0; e < s1; e += 64) {
        const int m = min(64, s1 - e);
        if (lane < m) {
            int src = csr_src[e + lane];
            float4 as = ((const float4*)a_s)[src];
            float v0 = as.x + ad.x; v0 = v0 > 0.f ? v0 : NEG * v0;
            float v1 = as.y + ad.y; v1 = v1 > 0.f ? v1 : NEG * v1;
            float v2 = as.z + ad.z; v2 = v2 > 0.f ? v2 : NEG * v2;
            float v3 = as.w + ad.w; v3 = v3 > 0.f ? v3 : NEG * v3;
            float e0 = __expf(v0); den0 += e0;
            float e1 = __expf(v1); den1 += e1;
            float e2 = __expf(v2); den2 += e2;
            float e3 = __expf(v3); den3 += e3;
            lds_src[wid][lane] = src;
            lds_ex[wid][lane]  = make_float4(e0, e1, e2, e3);
        }
        asm volatile("" ::: "memory");
#pragma unroll 2
        for (int j = 0; j < m; ++j) {
            int s = lds_src[wid][j];
            float wgt = ((const float*)&lds_ex[wid][j])[comp];  // broadcast ds_read_b32
            ushort4 u = hv4[(size_t)s * 64 + lane];
            a0 += wgt * __half2float(__ushort_as_half(u.x));
            a1 += wgt * __half2float(__ushort_as_half(u.y));
            a2 += wgt * __half2float(__ushort_as_half(u.z));
            a3 += wgt * __half2float(__ushort_as_half(u.w));
        }
        asm volatile("" ::: "memory");
    }
#pragma unroll
    for (int m = 32; m >= 1; m >>= 1) {
        den0 += __shfl_xor(den0, m, 64);
        den1 += __shfl_xor(den1, m, 64);
        den2 += __shfl_xor(den2, m, 64);
        den3 += __shfl_xor(den3, m, 64);
    }
    float d = (comp == 0) ? den0 : (comp == 1) ? den1 : (comp == 2) ? den2 : den3;
    float4 b = ((const float4*)bg)[lane];
    float o0 = a0 / d + b.x;
    float o1 = a1 / d + b.y;
    float o2 = a2 / d + b.z;
    float o3 = a3 / d + b.w;
    o0 = o0 > 0.f ? o0 : __expf(o0) - 1.f;
    o1 = o1 > 0.f ? o1 : __expf(o1) - 1.f;
    o2 = o2 > 0.f ? o2 : __expf(o2) - 1.f;
    o3 = o3 > 0.f ? o3 : __expf(o3) - 1.f;
    ushort4 u;
    u.x = __half_as_ushort(__float2half(o0));
    u.y = __half_as_ushort(__float2half(o1));
    u.z = __half_as_ushort(__float2half(o2));
    u.w = __half_as_ushort(__float2half(o3));
    ((ushort4*)xg)[(size_t)node * 64 + lane] = u;
    if (lane == 0) dinv[node] = rsqrtf((float)(s1 - s0));
}

// ---------------- GCN, wave-cooperative two-phase ----------------
__global__ __launch_bounds__(256) void gcn_half(const ushort* __restrict__ xw_half,
                                                const int* __restrict__ row_start,
                                                const int* __restrict__ csr_src,
                                                const float* __restrict__ dinv,
                                                const float* __restrict__ bc,
                                                float* __restrict__ xc) {
    __shared__ int   lds_src[4][64];
    __shared__ float lds_w[4][64];
    const int wid  = threadIdx.x >> 6;
    const int lane = threadIdx.x & 63;
    const int node = blockIdx.x * 4 + wid;
    if (node >= NN) return;
    const int s0 = row_start[node], s1 = row_start[node + 1];
    const float di = dinv[node];
    float ax = 0.f, ay = 0.f;
    const __half2* xw2 = (const __half2*)xw_half;

    for (int e = s0; e < s1; e += 64) {
        const int m = min(64, s1 - e);
        if (lane < m) {
            int s = csr_src[e + lane];
            lds_src[wid][lane] = s;
            lds_w[wid][lane]   = dinv[s] * di;
        }
        asm volatile("" ::: "memory");
#pragma unroll 2
        for (int j = 0; j < m; ++j) {
            int s = lds_src[wid][j];
            float wgt = lds_w[wid][j];
            float2 v = __half22float2(xw2[(size_t)s * 64 + lane]);
            ax += wgt * v.x; ay += wgt * v.y;
        }
        asm volatile("" ::: "memory");
    }
    float2 b = ((const float2*)bc)[lane];
    float o0 = ax + b.x, o1 = ay + b.y;
    ((float2*)(xc + (size_t)node * HID))[lane] =
        make_float2(o0 > 0.f ? o0 : 0.f, o1 > 0.f ? o1 : 0.f);
}

// ---------------- classifier + log_softmax ----------------
__global__ __launch_bounds__(256) void head_kernel(const float* __restrict__ xc,
                                                   const float* __restrict__ Wl,
                                                   const float* __restrict__ bl,
                                                   float* __restrict__ out) {
    int node = blockIdx.x * 4 + (threadIdx.x >> 6);
    int lane = threadIdx.x & 63;
    if (node >= NN) return;
    float x0 = xc[(size_t)node * HID + lane];
    float x1 = xc[(size_t)node * HID + 64 + lane];
    float p[NCLS];
#pragma unroll
    for (int j = 0; j < NCLS; ++j)
        p[j] = x0 * Wl[lane * NCLS + j] + x1 * Wl[(64 + lane) * NCLS + j];
#pragma unroll
    for (int m = 32; m >= 1; m >>= 1) {
#pragma unroll
        for (int j = 0; j < NCLS; ++j) p[j] += __shfl_xor(p[j], m, 64);
    }
#pragma unroll
    for (int j = 0; j < NCLS; ++j) p[j] += bl[j];
    float mx = p[0];
#pragma unroll
    for (int j = 1; j < NCLS; ++j) mx = fmaxf(mx, p[j]);
    float s = 0.f;
#pragma unroll
    for (int j = 0; j < NCLS; ++j) s += __expf(p[j] - mx);
    float ls = __logf(s);
    if (lane == 0) {
#pragma unroll
        for (int j = 0; j < NCLS; ++j) out[(size_t)node * NCLS + j] = p[j] - mx - ls;
    }
}

extern "C" void kernel_launch(void* const* d_in, const int* in_sizes, int n_in,
                              void* d_out, int out_size, void* d_ws, size_t ws_size,
                              hipStream_t stream) {
    const float* x       = (const float*)d_in[0];
    const float* Wg      = (const float*)d_in[2];
    const float* att_src = (const float*)d_in[3];
    const float* att_dst = (const float*)d_in[4];
    const float* bg      = (const float*)d_in[5];
    const float* Wc      = (const float*)d_in[6];
    const float* bc      = (const float*)d_in[7];
    const float* Wl      = (const float*)d_in[8];
    const float* bl      = (const float*)d_in[9];
    const int*   ei      = (const int*)d_in[10];
    float* out = (float*)d_out;

    char* p = (char*)d_ws;
    auto alloc = [&](size_t bytes) -> void* {
        void* r = (void*)p;
        p += (bytes + 255) & ~(size_t)255;
        return r;
    };
    ushort* h_half    = (ushort*)alloc((size_t)NN * HC * 2);
    ushort* xg_half   = (ushort*)alloc((size_t)NN * HC * 2);
    ushort* xw_half   = (ushort*)alloc((size_t)NN * HID * 2);
    float*  xc        = (float*)alloc((size_t)NN * HID * 4);
    float*  a_s       = (float*)alloc((size_t)NN * 4 * 4);
    float*  a_d       = (float*)alloc((size_t)NN * 4 * 4);
    int*    deg       = (int*)alloc((size_t)NN * 4);
    float*  dinv      = (float*)alloc((size_t)NN * 4);
    int*    row_start = (int*)alloc((size_t)(NN + 1) * 4);
    int*    cursor    = (int*)alloc((size_t)NN * 4);
    int*    csr_src   = (int*)alloc((size_t)E2 * 4);
    int*    blocksum  = (int*)alloc(256 * 4);
    ushort* wgt       = (ushort*)alloc((size_t)HC * FIN * 2);   // WgT fp16 [256][128]
    ushort* wct       = (ushort*)alloc((size_t)HID * HC * 2);   // WcT fp16 [128][256]

    hipMemsetAsync(deg, 0, (size_t)NN * 4, stream);
    hipMemsetAsync(cursor, 0, (size_t)NN * 4, stream);

    prep_kernel<<<1, 384, 0, stream>>>(Wg, Wc, wgt, wct);
    gemm1_mfma<<<625, 256, 0, stream>>>(x, wgt, att_src, att_dst, h_half, a_s, a_d);

    deg_kernel<<<(EE + 255) / 256, 256, 0, stream>>>(ei, deg);
    scan_a<<<(NN + 255) / 256, 256, 0, stream>>>(deg, row_start, blocksum);
    scan_b<<<1, 256, 0, stream>>>(blocksum, (NN + 255) / 256);
    scan_c<<<(NN + 255) / 256, 256, 0, stream>>>(row_start, blocksum);
    scatter_kernel<<<(E2 + 255) / 256, 256, 0, stream>>>(ei, row_start, cursor, csr_src);

    gat_half<<<(NN + 3) / 4, 256, 0, stream>>>(h_half, a_s, a_d, row_start, csr_src, bg, xg_half, dinv);
    gemm2_mfma<<<625, 256, 0, stream>>>(xg_half, wct, xw_half);
    gcn_half<<<(NN + 3) / 4, 256, 0, stream>>>(xw_half, row_start, csr_src, dinv, bc, xc);
    head_kernel<<<(NN + 3) / 4, 256, 0, stream>>>(xc, Wl, bl, out);
}

// Round 5
// 272.365 us; speedup vs baseline: 2.0475x; 1.0836x over previous
//
#include <hip/hip_runtime.h>
#include <hip/hip_fp16.h>
#include <math.h>

#define NN 50000
#define EE 800000
#define E2 (EE + NN)
#define FIN 128
#define HC 256
#define HID 128
#define NCLS 10
#define NEG 0.2f

typedef _Float16 f16x8 __attribute__((ext_vector_type(8)));
typedef float f32x4 __attribute__((ext_vector_type(4)));

__device__ inline f16x8 cvt8(float4 a, float4 b) {
    f16x8 r;
    r[0] = (_Float16)a.x; r[1] = (_Float16)a.y; r[2] = (_Float16)a.z; r[3] = (_Float16)a.w;
    r[4] = (_Float16)b.x; r[5] = (_Float16)b.y; r[6] = (_Float16)b.z; r[7] = (_Float16)b.w;
    return r;
}

// ---------------- prep: WgT_h[256][128], WcT_h[128][256] (fp16, transposed) ----------------
__global__ __launch_bounds__(384) void prep_kernel(const float* __restrict__ Wg,
                                                   const float* __restrict__ Wc,
                                                   ushort* __restrict__ wgt,
                                                   ushort* __restrict__ wct) {
    int t = threadIdx.x;
    if (t < 256) {
        for (int k = 0; k < FIN; ++k)
            wgt[t * FIN + k] = __half_as_ushort(__float2half(Wg[k * HC + t]));
    } else {
        int c = t - 256;
        for (int k = 0; k < HC; ++k)
            wct[c * HC + k] = __half_as_ushort(__float2half(Wc[k * HID + c]));
    }
}

// ---------------- GEMM1 (MFMA): h = x@Wg -> fp16 linear, a_s/a_d in epilogue ----------------
__global__ __launch_bounds__(256) void gemm1_mfma(const float* __restrict__ x,
                                                  const ushort* __restrict__ wgt,
                                                  const float* __restrict__ att_s,
                                                  const float* __restrict__ att_d,
                                                  ushort* __restrict__ h_half,
                                                  float* __restrict__ a_s,
                                                  float* __restrict__ a_d) {
    const int t = threadIdx.x;
    const int w  = t >> 6;
    const int l  = t & 63;
    const int lr = l & 15;
    const int lg = l >> 4;

    f16x8 bf[4][4];
#pragma unroll
    for (int ct = 0; ct < 4; ++ct)
#pragma unroll
        for (int ks = 0; ks < 4; ++ks)
            bf[ct][ks] = *(const f16x8*)(wgt + (size_t)(64 * w + 16 * ct + lr) * FIN + ks * 32 + 8 * lg);

    float asv[4], adv[4];
#pragma unroll
    for (int ct = 0; ct < 4; ++ct) {
        asv[ct] = att_s[w * 64 + 16 * ct + lr];
        adv[ct] = att_d[w * 64 + 16 * ct + lr];
    }

    for (int rt = blockIdx.x; rt < 3125; rt += gridDim.x) {
        const int r0 = rt * 16;
        f32x4 acc[4];
#pragma unroll
        for (int ct = 0; ct < 4; ++ct) acc[ct] = (f32x4){0.f, 0.f, 0.f, 0.f};

#pragma unroll
        for (int ks = 0; ks < 4; ++ks) {
            const float4* xp = (const float4*)(x + (size_t)(r0 + lr) * FIN + ks * 32 + 8 * lg);
            f16x8 af = cvt8(xp[0], xp[1]);
#pragma unroll
            for (int ct = 0; ct < 4; ++ct)
                acc[ct] = __builtin_amdgcn_mfma_f32_16x16x32_f16(af, bf[ct][ks], acc[ct], 0, 0, 0);
        }
#pragma unroll
        for (int j = 0; j < 4; ++j) {
            const int row = r0 + 4 * lg + j;
#pragma unroll
            for (int ct = 0; ct < 4; ++ct)
                h_half[(size_t)row * HC + 64 * w + 16 * ct + lr] =
                    __half_as_ushort(__float2half(acc[ct][j]));
            float ps = 0.f, pd = 0.f;
#pragma unroll
            for (int ct = 0; ct < 4; ++ct) {
                ps += acc[ct][j] * asv[ct];
                pd += acc[ct][j] * adv[ct];
            }
#pragma unroll
            for (int m = 8; m >= 1; m >>= 1) {
                ps += __shfl_xor(ps, m, 64);
                pd += __shfl_xor(pd, m, 64);
            }
            if (lr == 0) {
                a_s[row * 4 + w] = ps;
                a_d[row * 4 + w] = pd;
            }
        }
    }
}

// ---------------- GEMM2 (MFMA): xw = xg(fp16)@Wc -> fp16 linear ----------------
__global__ __launch_bounds__(256) void gemm2_mfma(const ushort* __restrict__ xg,
                                                  const ushort* __restrict__ wct,
                                                  ushort* __restrict__ xw) {
    const int t = threadIdx.x;
    const int w  = t >> 6;
    const int l  = t & 63;
    const int lr = l & 15;
    const int lg = l >> 4;

    f16x8 bf[2][8];
#pragma unroll
    for (int ct = 0; ct < 2; ++ct)
#pragma unroll
        for (int ks = 0; ks < 8; ++ks)
            bf[ct][ks] = *(const f16x8*)(wct + (size_t)(32 * w + 16 * ct + lr) * HC + ks * 32 + 8 * lg);

    for (int rt = blockIdx.x; rt < 3125; rt += gridDim.x) {
        const int r0 = rt * 16;
        f32x4 acc[2];
        acc[0] = (f32x4){0.f, 0.f, 0.f, 0.f};
        acc[1] = (f32x4){0.f, 0.f, 0.f, 0.f};
#pragma unroll
        for (int ks = 0; ks < 8; ++ks) {
            f16x8 af = *(const f16x8*)(xg + (size_t)(r0 + lr) * HC + ks * 32 + 8 * lg);
            acc[0] = __builtin_amdgcn_mfma_f32_16x16x32_f16(af, bf[0][ks], acc[0], 0, 0, 0);
            acc[1] = __builtin_amdgcn_mfma_f32_16x16x32_f16(af, bf[1][ks], acc[1], 0, 0, 0);
        }
#pragma unroll
        for (int j = 0; j < 4; ++j) {
            const int row = r0 + 4 * lg + j;
#pragma unroll
            for (int ct = 0; ct < 2; ++ct)
                xw[(size_t)row * HID + 32 * w + 16 * ct + lr] =
                    __half_as_ushort(__float2half(acc[ct][j]));
        }
    }
}

// ---------------- CSR build ----------------
__global__ __launch_bounds__(256) void deg_kernel(const int* __restrict__ ei, int* __restrict__ deg) {
    int e4 = blockIdx.x * 256 + threadIdx.x;
    if (e4 * 4 >= EE) return;
    int4 d = ((const int4*)(ei + EE))[e4];
    atomicAdd(&deg[d.x], 1);
    atomicAdd(&deg[d.y], 1);
    atomicAdd(&deg[d.z], 1);
    atomicAdd(&deg[d.w], 1);
}

__global__ __launch_bounds__(256) void scan_a(const int* __restrict__ deg, int* __restrict__ row_start,
                                              int* __restrict__ blocksum) {
    __shared__ int sh[256];
    int t = threadIdx.x;
    int i = blockIdx.x * 256 + t;
    int v = (i < NN) ? (deg[i] + 1) : 0;
    sh[t] = v;
    __syncthreads();
#pragma unroll
    for (int off = 1; off < 256; off <<= 1) {
        int y = (t >= off) ? sh[t - off] : 0;
        __syncthreads();
        sh[t] += y;
        __syncthreads();
    }
    if (i < NN) row_start[i] = sh[t] - v;
    if (t == 255) blocksum[blockIdx.x] = sh[255];
}

__global__ __launch_bounds__(256) void scan_b(int* __restrict__ bs, int nb) {
    __shared__ int sh[256];
    int t = threadIdx.x;
    int v = (t < nb) ? bs[t] : 0;
    sh[t] = v;
    __syncthreads();
#pragma unroll
    for (int off = 1; off < 256; off <<= 1) {
        int y = (t >= off) ? sh[t - off] : 0;
        __syncthreads();
        sh[t] += y;
        __syncthreads();
    }
    if (t < nb) bs[t] = sh[t] - v;
}

__global__ __launch_bounds__(256) void scan_c(int* __restrict__ row_start, const int* __restrict__ bs) {
    int i = blockIdx.x * 256 + threadIdx.x;
    if (i < NN) row_start[i] += bs[blockIdx.x];
    if (i == 0) row_start[NN] = E2;
}

__global__ __launch_bounds__(256) void scatter_kernel(const int* __restrict__ ei,
                                                      const int* __restrict__ row_start,
                                                      int* __restrict__ cursor,
                                                      int* __restrict__ csr_src) {
    int e = blockIdx.x * 256 + threadIdx.x;
    if (e >= E2) return;
    int src, dst;
    if (e < EE) { src = ei[e]; dst = ei[EE + e]; }
    else        { src = dst = e - EE; }
    int pos = row_start[dst] + atomicAdd(&cursor[dst], 1);
    csr_src[pos] = src;
}

// ---------------- fused GAT, wave-cooperative two-phase, unroll-4 gather ----------------
__global__ __launch_bounds__(256) void gat_half(const ushort* __restrict__ h_half,
                                                const float* __restrict__ a_s,
                                                const float* __restrict__ a_d,
                                                const int* __restrict__ row_start,
                                                const int* __restrict__ csr_src,
                                                const float* __restrict__ bg,
                                                ushort* __restrict__ xg,
                                                float* __restrict__ dinv) {
    __shared__ int    lds_off[4][64];   // src * 64 (ushort4 index base)
    __shared__ float4 lds_ex[4][64];
    const int wid  = threadIdx.x >> 6;
    const int lane = threadIdx.x & 63;
    const int node = blockIdx.x * 4 + wid;
    if (node >= NN) return;
    const int s0 = row_start[node], s1 = row_start[node + 1];
    const float4 ad = ((const float4*)a_d)[node];
    const int comp = lane >> 4;

    float den0 = 0.f, den1 = 0.f, den2 = 0.f, den3 = 0.f;
    float a0 = 0.f, a1 = 0.f, a2 = 0.f, a3 = 0.f;
    const ushort4* hv4 = (const ushort4*)h_half;
    const float* exb = (const float*)&lds_ex[wid][0];

    for (int e = s0; e < s1; e += 64) {
        const int m = min(64, s1 - e);
        if (lane < m) {
            int src = csr_src[e + lane];
            float4 as = ((const float4*)a_s)[src];
            float v0 = as.x + ad.x; v0 = v0 > 0.f ? v0 : NEG * v0;
            float v1 = as.y + ad.y; v1 = v1 > 0.f ? v1 : NEG * v1;
            float v2 = as.z + ad.z; v2 = v2 > 0.f ? v2 : NEG * v2;
            float v3 = as.w + ad.w; v3 = v3 > 0.f ? v3 : NEG * v3;
            float e0 = __expf(v0); den0 += e0;
            float e1 = __expf(v1); den1 += e1;
            float e2 = __expf(v2); den2 += e2;
            float e3 = __expf(v3); den3 += e3;
            lds_off[wid][lane] = src * 64;
            lds_ex[wid][lane]  = make_float4(e0, e1, e2, e3);
        }
        asm volatile("" ::: "memory");
        int j = 0;
        for (; j + 4 <= m; j += 4) {
            int i0 = lds_off[wid][j]     + lane;
            int i1 = lds_off[wid][j + 1] + lane;
            int i2 = lds_off[wid][j + 2] + lane;
            int i3 = lds_off[wid][j + 3] + lane;
            float w0 = exb[(j)     * 4 + comp];
            float w1 = exb[(j + 1) * 4 + comp];
            float w2 = exb[(j + 2) * 4 + comp];
            float w3 = exb[(j + 3) * 4 + comp];
            ushort4 u0 = hv4[i0];
            ushort4 u1 = hv4[i1];
            ushort4 u2 = hv4[i2];
            ushort4 u3 = hv4[i3];
            a0 += w0 * __half2float(__ushort_as_half(u0.x));
            a1 += w0 * __half2float(__ushort_as_half(u0.y));
            a2 += w0 * __half2float(__ushort_as_half(u0.z));
            a3 += w0 * __half2float(__ushort_as_half(u0.w));
            a0 += w1 * __half2float(__ushort_as_half(u1.x));
            a1 += w1 * __half2float(__ushort_as_half(u1.y));
            a2 += w1 * __half2float(__ushort_as_half(u1.z));
            a3 += w1 * __half2float(__ushort_as_half(u1.w));
            a0 += w2 * __half2float(__ushort_as_half(u2.x));
            a1 += w2 * __half2float(__ushort_as_half(u2.y));
            a2 += w2 * __half2float(__ushort_as_half(u2.z));
            a3 += w2 * __half2float(__ushort_as_half(u2.w));
            a0 += w3 * __half2float(__ushort_as_half(u3.x));
            a1 += w3 * __half2float(__ushort_as_half(u3.y));
            a2 += w3 * __half2float(__ushort_as_half(u3.z));
            a3 += w3 * __half2float(__ushort_as_half(u3.w));
        }
        for (; j < m; ++j) {
            int i0 = lds_off[wid][j] + lane;
            float w0 = exb[j * 4 + comp];
            ushort4 u0 = hv4[i0];
            a0 += w0 * __half2float(__ushort_as_half(u0.x));
            a1 += w0 * __half2float(__ushort_as_half(u0.y));
            a2 += w0 * __half2float(__ushort_as_half(u0.z));
            a3 += w0 * __half2float(__ushort_as_half(u0.w));
        }
        asm volatile("" ::: "memory");
    }
#pragma unroll
    for (int m = 32; m >= 1; m >>= 1) {
        den0 += __shfl_xor(den0, m, 64);
        den1 += __shfl_xor(den1, m, 64);
        den2 += __shfl_xor(den2, m, 64);
        den3 += __shfl_xor(den3, m, 64);
    }
    float d = (comp == 0) ? den0 : (comp == 1) ? den1 : (comp == 2) ? den2 : den3;
    float4 b = ((const float4*)bg)[lane];
    float o0 = a0 / d + b.x;
    float o1 = a1 / d + b.y;
    float o2 = a2 / d + b.z;
    float o3 = a3 / d + b.w;
    o0 = o0 > 0.f ? o0 : __expf(o0) - 1.f;
    o1 = o1 > 0.f ? o1 : __expf(o1) - 1.f;
    o2 = o2 > 0.f ? o2 : __expf(o2) - 1.f;
    o3 = o3 > 0.f ? o3 : __expf(o3) - 1.f;
    ushort4 u;
    u.x = __half_as_ushort(__float2half(o0));
    u.y = __half_as_ushort(__float2half(o1));
    u.z = __half_as_ushort(__float2half(o2));
    u.w = __half_as_ushort(__float2half(o3));
    ((ushort4*)xg)[(size_t)node * 64 + lane] = u;
    if (lane == 0) dinv[node] = rsqrtf((float)(s1 - s0));
}

// ---------------- GCN + classifier head fused (xc never hits memory) ----------------
__global__ __launch_bounds__(256) void gcn_head(const ushort* __restrict__ xw_half,
                                                const int* __restrict__ row_start,
                                                const int* __restrict__ csr_src,
                                                const float* __restrict__ dinv,
                                                const float* __restrict__ bc,
                                                const float* __restrict__ Wl,
                                                const float* __restrict__ bl,
                                                float* __restrict__ out) {
    __shared__ int   lds_off[4][64];   // src * 64 (half2 index base)
    __shared__ float lds_w[4][64];
    const int wid  = threadIdx.x >> 6;
    const int lane = threadIdx.x & 63;
    const int node = blockIdx.x * 4 + wid;
    if (node >= NN) return;
    const int s0 = row_start[node], s1 = row_start[node + 1];
    const float di = dinv[node];
    float ax = 0.f, ay = 0.f;
    const __half2* xw2 = (const __half2*)xw_half;

    for (int e = s0; e < s1; e += 64) {
        const int m = min(64, s1 - e);
        if (lane < m) {
            int s = csr_src[e + lane];
            lds_off[wid][lane] = s * 64;
            lds_w[wid][lane]   = dinv[s] * di;
        }
        asm volatile("" ::: "memory");
        int j = 0;
        for (; j + 4 <= m; j += 4) {
            int i0 = lds_off[wid][j]     + lane;
            int i1 = lds_off[wid][j + 1] + lane;
            int i2 = lds_off[wid][j + 2] + lane;
            int i3 = lds_off[wid][j + 3] + lane;
            float w0 = lds_w[wid][j];
            float w1 = lds_w[wid][j + 1];
            float w2 = lds_w[wid][j + 2];
            float w3 = lds_w[wid][j + 3];
            float2 v0 = __half22float2(xw2[i0]);
            float2 v1 = __half22float2(xw2[i1]);
            float2 v2 = __half22float2(xw2[i2]);
            float2 v3 = __half22float2(xw2[i3]);
            ax += w0 * v0.x; ay += w0 * v0.y;
            ax += w1 * v1.x; ay += w1 * v1.y;
            ax += w2 * v2.x; ay += w2 * v2.y;
            ax += w3 * v3.x; ay += w3 * v3.y;
        }
        for (; j < m; ++j) {
            int i0 = lds_off[wid][j] + lane;
            float w0 = lds_w[wid][j];
            float2 v0 = __half22float2(xw2[i0]);
            ax += w0 * v0.x; ay += w0 * v0.y;
        }
        asm volatile("" ::: "memory");
    }
    // xc cols {2*lane, 2*lane+1}
    float2 b = ((const float2*)bc)[lane];
    float o0 = ax + b.x; o0 = o0 > 0.f ? o0 : 0.f;
    float o1 = ay + b.y; o1 = o1 > 0.f ? o1 : 0.f;

    // classifier: p[j] = sum over 128 cols of xc*Wl
    float p[NCLS];
#pragma unroll
    for (int j = 0; j < NCLS; ++j)
        p[j] = o0 * Wl[(2 * lane) * NCLS + j] + o1 * Wl[(2 * lane + 1) * NCLS + j];
#pragma unroll
    for (int m = 32; m >= 1; m >>= 1) {
#pragma unroll
        for (int j = 0; j < NCLS; ++j) p[j] += __shfl_xor(p[j], m, 64);
    }
#pragma unroll
    for (int j = 0; j < NCLS; ++j) p[j] += bl[j];
    float mx = p[0];
#pragma unroll
    for (int j = 1; j < NCLS; ++j) mx = fmaxf(mx, p[j]);
    float s = 0.f;
#pragma unroll
    for (int j = 0; j < NCLS; ++j) s += __expf(p[j] - mx);
    float ls = __logf(s);
    if (lane == 0) {
#pragma unroll
        for (int j = 0; j < NCLS; ++j) out[(size_t)node * NCLS + j] = p[j] - mx - ls;
    }
}

extern "C" void kernel_launch(void* const* d_in, const int* in_sizes, int n_in,
                              void* d_out, int out_size, void* d_ws, size_t ws_size,
                              hipStream_t stream) {
    const float* x       = (const float*)d_in[0];
    const float* Wg      = (const float*)d_in[2];
    const float* att_src = (const float*)d_in[3];
    const float* att_dst = (const float*)d_in[4];
    const float* bg      = (const float*)d_in[5];
    const float* Wc      = (const float*)d_in[6];
    const float* bc      = (const float*)d_in[7];
    const float* Wl      = (const float*)d_in[8];
    const float* bl      = (const float*)d_in[9];
    const int*   ei      = (const int*)d_in[10];
    float* out = (float*)d_out;

    char* p = (char*)d_ws;
    auto alloc = [&](size_t bytes) -> void* {
        void* r = (void*)p;
        p += (bytes + 255) & ~(size_t)255;
        return r;
    };
    ushort* h_half    = (ushort*)alloc((size_t)NN * HC * 2);
    ushort* xg_half   = (ushort*)alloc((size_t)NN * HC * 2);
    ushort* xw_half   = (ushort*)alloc((size_t)NN * HID * 2);
    float*  a_s       = (float*)alloc((size_t)NN * 4 * 4);
    float*  a_d       = (float*)alloc((size_t)NN * 4 * 4);
    int*    deg       = (int*)alloc((size_t)NN * 4);
    float*  dinv      = (float*)alloc((size_t)NN * 4);
    int*    row_start = (int*)alloc((size_t)(NN + 1) * 4);
    int*    cursor    = (int*)alloc((size_t)NN * 4);
    int*    csr_src   = (int*)alloc((size_t)E2 * 4);
    int*    blocksum  = (int*)alloc(256 * 4);
    ushort* wgt       = (ushort*)alloc((size_t)HC * FIN * 2);
    ushort* wct       = (ushort*)alloc((size_t)HID * HC * 2);

    hipMemsetAsync(deg, 0, (size_t)NN * 4, stream);
    hipMemsetAsync(cursor, 0, (size_t)NN * 4, stream);

    prep_kernel<<<1, 384, 0, stream>>>(Wg, Wc, wgt, wct);
    gemm1_mfma<<<625, 256, 0, stream>>>(x, wgt, att_src, att_dst, h_half, a_s, a_d);

    deg_kernel<<<(EE / 4 + 255) / 256, 256, 0, stream>>>(ei, deg);
    scan_a<<<(NN + 255) / 256, 256, 0, stream>>>(deg, row_start, blocksum);
    scan_b<<<1, 256, 0, stream>>>(blocksum, (NN + 255) / 256);
    scan_c<<<(NN + 255) / 256, 256, 0, stream>>>(row_start, blocksum);
    scatter_kernel<<<(E2 + 255) / 256, 256, 0, stream>>>(ei, row_start, cursor, csr_src);

    gat_half<<<(NN + 3) / 4, 256, 0, stream>>>(h_half, a_s, a_d, row_start, csr_src, bg, xg_half, dinv);
    gemm2_mfma<<<625, 256, 0, stream>>>(xg_half, wct, xw_half);
    gcn_head<<<(NN + 3) / 4, 256, 0, stream>>>(xw_half, row_start, csr_src, dinv, bc, Wl, bl, out);
}

// Round 6
// 254.116 us; speedup vs baseline: 2.1945x; 1.0718x over previous
//
#include <hip/hip_runtime.h>
#include <hip/hip_fp16.h>
#include <math.h>

#define NN 50000
#define EE 800000
#define E2 (EE + NN)
#define FIN 128
#define HC 256
#define HID 128
#define NCLS 10
#define NEG 0.2f

typedef _Float16 f16x8 __attribute__((ext_vector_type(8)));
typedef float f32x4 __attribute__((ext_vector_type(4)));

// fp32 acc += fp16(lo/hi of u) * fp32 w   (VOP3P mixed-precision FMA)
#define FMA_MIX_LO(acc, u, w) \
    asm("v_fma_mix_f32 %0, %1, %2, %0 op_sel:[0,0,0] op_sel_hi:[1,0,0]" \
        : "+v"(acc) : "v"(u), "v"(w))
#define FMA_MIX_HI(acc, u, w) \
    asm("v_fma_mix_f32 %0, %1, %2, %0 op_sel:[1,0,0] op_sel_hi:[1,0,0]" \
        : "+v"(acc) : "v"(u), "v"(w))

__device__ inline f16x8 cvt8(float4 a, float4 b) {
    f16x8 r;
    r[0] = (_Float16)a.x; r[1] = (_Float16)a.y; r[2] = (_Float16)a.z; r[3] = (_Float16)a.w;
    r[4] = (_Float16)b.x; r[5] = (_Float16)b.y; r[6] = (_Float16)b.z; r[7] = (_Float16)b.w;
    return r;
}

// ---------------- prep: WgT_h[256][128], WcT_h[128][256] (fp16, transposed) ----------------
__global__ __launch_bounds__(256) void prep_kernel(const float* __restrict__ Wg,
                                                   const float* __restrict__ Wc,
                                                   ushort* __restrict__ wgt,
                                                   ushort* __restrict__ wct) {
    int i = blockIdx.x * 256 + threadIdx.x;   // 32768 of each
    if (i < HC * FIN) {
        int c = i & 255, k = i >> 8;          // read Wg coalesced
        wgt[c * FIN + k] = __half_as_ushort(__float2half(Wg[i]));
        int c2 = i & 127, k2 = i >> 7;        // read Wc coalesced
        wct[c2 * HC + k2] = __half_as_ushort(__float2half(Wc[i]));
    }
}

// ---------------- GEMM1 (MFMA): h = x@Wg -> fp16 linear, a_s/a_d in epilogue ----------------
__global__ __launch_bounds__(256) void gemm1_mfma(const float* __restrict__ x,
                                                  const ushort* __restrict__ wgt,
                                                  const float* __restrict__ att_s,
                                                  const float* __restrict__ att_d,
                                                  ushort* __restrict__ h_half,
                                                  float* __restrict__ a_s,
                                                  float* __restrict__ a_d) {
    const int t = threadIdx.x;
    const int w  = t >> 6;
    const int l  = t & 63;
    const int lr = l & 15;
    const int lg = l >> 4;

    f16x8 bf[4][4];
#pragma unroll
    for (int ct = 0; ct < 4; ++ct)
#pragma unroll
        for (int ks = 0; ks < 4; ++ks)
            bf[ct][ks] = *(const f16x8*)(wgt + (size_t)(64 * w + 16 * ct + lr) * FIN + ks * 32 + 8 * lg);

    float asv[4], adv[4];
#pragma unroll
    for (int ct = 0; ct < 4; ++ct) {
        asv[ct] = att_s[w * 64 + 16 * ct + lr];
        adv[ct] = att_d[w * 64 + 16 * ct + lr];
    }

    for (int rt = blockIdx.x; rt < 3125; rt += gridDim.x) {
        const int r0 = rt * 16;
        f32x4 acc[4];
#pragma unroll
        for (int ct = 0; ct < 4; ++ct) acc[ct] = (f32x4){0.f, 0.f, 0.f, 0.f};

#pragma unroll
        for (int ks = 0; ks < 4; ++ks) {
            const float4* xp = (const float4*)(x + (size_t)(r0 + lr) * FIN + ks * 32 + 8 * lg);
            f16x8 af = cvt8(xp[0], xp[1]);
#pragma unroll
            for (int ct = 0; ct < 4; ++ct)
                acc[ct] = __builtin_amdgcn_mfma_f32_16x16x32_f16(af, bf[ct][ks], acc[ct], 0, 0, 0);
        }
#pragma unroll
        for (int j = 0; j < 4; ++j) {
            const int row = r0 + 4 * lg + j;
#pragma unroll
            for (int ct = 0; ct < 4; ++ct)
                h_half[(size_t)row * HC + 64 * w + 16 * ct + lr] =
                    __half_as_ushort(__float2half(acc[ct][j]));
            float ps = 0.f, pd = 0.f;
#pragma unroll
            for (int ct = 0; ct < 4; ++ct) {
                ps += acc[ct][j] * asv[ct];
                pd += acc[ct][j] * adv[ct];
            }
#pragma unroll
            for (int m = 8; m >= 1; m >>= 1) {
                ps += __shfl_xor(ps, m, 64);
                pd += __shfl_xor(pd, m, 64);
            }
            if (lr == 0) {
                a_s[row * 4 + w] = ps;
                a_d[row * 4 + w] = pd;
            }
        }
    }
}

// ---------------- GEMM2 (MFMA): xw = xg(fp16)@Wc -> fp16 linear ----------------
__global__ __launch_bounds__(256) void gemm2_mfma(const ushort* __restrict__ xg,
                                                  const ushort* __restrict__ wct,
                                                  ushort* __restrict__ xw) {
    const int t = threadIdx.x;
    const int w  = t >> 6;
    const int l  = t & 63;
    const int lr = l & 15;
    const int lg = l >> 4;

    f16x8 bf[2][8];
#pragma unroll
    for (int ct = 0; ct < 2; ++ct)
#pragma unroll
        for (int ks = 0; ks < 8; ++ks)
            bf[ct][ks] = *(const f16x8*)(wct + (size_t)(32 * w + 16 * ct + lr) * HC + ks * 32 + 8 * lg);

    for (int rt = blockIdx.x; rt < 3125; rt += gridDim.x) {
        const int r0 = rt * 16;
        f32x4 acc[2];
        acc[0] = (f32x4){0.f, 0.f, 0.f, 0.f};
        acc[1] = (f32x4){0.f, 0.f, 0.f, 0.f};
#pragma unroll
        for (int ks = 0; ks < 8; ++ks) {
            f16x8 af = *(const f16x8*)(xg + (size_t)(r0 + lr) * HC + ks * 32 + 8 * lg);
            acc[0] = __builtin_amdgcn_mfma_f32_16x16x32_f16(af, bf[0][ks], acc[0], 0, 0, 0);
            acc[1] = __builtin_amdgcn_mfma_f32_16x16x32_f16(af, bf[1][ks], acc[1], 0, 0, 0);
        }
#pragma unroll
        for (int j = 0; j < 4; ++j) {
            const int row = r0 + 4 * lg + j;
#pragma unroll
            for (int ct = 0; ct < 2; ++ct)
                xw[(size_t)row * HID + 32 * w + 16 * ct + lr] =
                    __half_as_ushort(__float2half(acc[ct][j]));
        }
    }
}

// ---------------- CSR build ----------------
__global__ __launch_bounds__(256) void deg_kernel(const int* __restrict__ ei, int* __restrict__ deg) {
    int e4 = blockIdx.x * 256 + threadIdx.x;
    if (e4 * 4 >= EE) return;
    int4 d = ((const int4*)(ei + EE))[e4];
    atomicAdd(&deg[d.x], 1);
    atomicAdd(&deg[d.y], 1);
    atomicAdd(&deg[d.z], 1);
    atomicAdd(&deg[d.w], 1);
}

__global__ __launch_bounds__(256) void scan_a(const int* __restrict__ deg, int* __restrict__ row_start,
                                              int* __restrict__ blocksum) {
    __shared__ int sh[256];
    int t = threadIdx.x;
    int i = blockIdx.x * 256 + t;
    int v = (i < NN) ? (deg[i] + 1) : 0;
    sh[t] = v;
    __syncthreads();
#pragma unroll
    for (int off = 1; off < 256; off <<= 1) {
        int y = (t >= off) ? sh[t - off] : 0;
        __syncthreads();
        sh[t] += y;
        __syncthreads();
    }
    if (i < NN) row_start[i] = sh[t] - v;
    if (t == 255) blocksum[blockIdx.x] = sh[255];
}

__global__ __launch_bounds__(256) void scan_b(int* __restrict__ bs, int nb) {
    __shared__ int sh[256];
    int t = threadIdx.x;
    int v = (t < nb) ? bs[t] : 0;
    sh[t] = v;
    __syncthreads();
#pragma unroll
    for (int off = 1; off < 256; off <<= 1) {
        int y = (t >= off) ? sh[t - off] : 0;
        __syncthreads();
        sh[t] += y;
        __syncthreads();
    }
    if (t < nb) bs[t] = sh[t] - v;
}

__global__ __launch_bounds__(256) void scan_c(int* __restrict__ row_start, const int* __restrict__ bs) {
    int i = blockIdx.x * 256 + threadIdx.x;
    if (i < NN) row_start[i] += bs[blockIdx.x];
    if (i == 0) row_start[NN] = E2;
}

__global__ __launch_bounds__(256) void scatter_kernel(const int* __restrict__ ei,
                                                      const int* __restrict__ row_start,
                                                      int* __restrict__ cursor,
                                                      int* __restrict__ csr_src) {
    int e = blockIdx.x * 256 + threadIdx.x;
    if (e >= E2) return;
    int src, dst;
    if (e < EE) { src = ei[e]; dst = ei[EE + e]; }
    else        { src = dst = e - EE; }
    int pos = row_start[dst] + atomicAdd(&cursor[dst], 1);
    csr_src[pos] = src;
}

// ---------------- fused GAT: two-phase, packed (off,w) ds_read_b64, fma_mix ----------------
__global__ __launch_bounds__(256) void gat_half(const ushort* __restrict__ h_half,
                                                const float* __restrict__ a_s,
                                                const float* __restrict__ a_d,
                                                const int* __restrict__ row_start,
                                                const int* __restrict__ csr_src,
                                                const float* __restrict__ bg,
                                                ushort* __restrict__ xg,
                                                float* __restrict__ dinv) {
    __shared__ int2 lds_ow[4][4 * 65];   // [wid][comp*65 + j] = {byte_off, w_bits}
    const int wid  = threadIdx.x >> 6;
    const int lane = threadIdx.x & 63;
    const int node = blockIdx.x * 4 + wid;
    if (node >= NN) return;
    const int s0 = row_start[node], s1 = row_start[node + 1];
    const float4 ad = ((const float4*)a_d)[node];
    const int comp = lane >> 4;

    float den0 = 0.f, den1 = 0.f, den2 = 0.f, den3 = 0.f;
    float a0 = 0.f, a1 = 0.f, a2 = 0.f, a3 = 0.f;
    const char* hlane = (const char*)h_half + lane * 8;   // lane's 8B within a 512B row
    const int2* myow = &lds_ow[wid][comp * 65];

    for (int e = s0; e < s1; e += 64) {
        const int m = min(64, s1 - e);
        if (lane < m) {
            int src = csr_src[e + lane];
            float4 as = ((const float4*)a_s)[src];
            float v0 = as.x + ad.x; v0 = v0 > 0.f ? v0 : NEG * v0;
            float v1 = as.y + ad.y; v1 = v1 > 0.f ? v1 : NEG * v1;
            float v2 = as.z + ad.z; v2 = v2 > 0.f ? v2 : NEG * v2;
            float v3 = as.w + ad.w; v3 = v3 > 0.f ? v3 : NEG * v3;
            float e0 = __expf(v0); den0 += e0;
            float e1 = __expf(v1); den1 += e1;
            float e2 = __expf(v2); den2 += e2;
            float e3 = __expf(v3); den3 += e3;
            int boff = src * 512;
            lds_ow[wid][0 * 65 + lane] = make_int2(boff, __float_as_int(e0));
            lds_ow[wid][1 * 65 + lane] = make_int2(boff, __float_as_int(e1));
            lds_ow[wid][2 * 65 + lane] = make_int2(boff, __float_as_int(e2));
            lds_ow[wid][3 * 65 + lane] = make_int2(boff, __float_as_int(e3));
        }
        asm volatile("s_waitcnt lgkmcnt(0)" ::: "memory");
        int j = 0;
        for (; j + 4 <= m; j += 4) {
            int2 ow0 = myow[j];
            int2 ow1 = myow[j + 1];
            int2 ow2 = myow[j + 2];
            int2 ow3 = myow[j + 3];
            uint2 u0 = *(const uint2*)(hlane + ow0.x);
            uint2 u1 = *(const uint2*)(hlane + ow1.x);
            uint2 u2 = *(const uint2*)(hlane + ow2.x);
            uint2 u3 = *(const uint2*)(hlane + ow3.x);
            float w0 = __int_as_float(ow0.y);
            float w1 = __int_as_float(ow1.y);
            float w2 = __int_as_float(ow2.y);
            float w3 = __int_as_float(ow3.y);
            FMA_MIX_LO(a0, u0.x, w0); FMA_MIX_HI(a1, u0.x, w0);
            FMA_MIX_LO(a2, u0.y, w0); FMA_MIX_HI(a3, u0.y, w0);
            FMA_MIX_LO(a0, u1.x, w1); FMA_MIX_HI(a1, u1.x, w1);
            FMA_MIX_LO(a2, u1.y, w1); FMA_MIX_HI(a3, u1.y, w1);
            FMA_MIX_LO(a0, u2.x, w2); FMA_MIX_HI(a1, u2.x, w2);
            FMA_MIX_LO(a2, u2.y, w2); FMA_MIX_HI(a3, u2.y, w2);
            FMA_MIX_LO(a0, u3.x, w3); FMA_MIX_HI(a1, u3.x, w3);
            FMA_MIX_LO(a2, u3.y, w3); FMA_MIX_HI(a3, u3.y, w3);
        }
        for (; j < m; ++j) {
            int2 ow = myow[j];
            uint2 u = *(const uint2*)(hlane + ow.x);
            float w = __int_as_float(ow.y);
            FMA_MIX_LO(a0, u.x, w); FMA_MIX_HI(a1, u.x, w);
            FMA_MIX_LO(a2, u.y, w); FMA_MIX_HI(a3, u.y, w);
        }
        asm volatile("" ::: "memory");
    }
#pragma unroll
    for (int m = 32; m >= 1; m >>= 1) {
        den0 += __shfl_xor(den0, m, 64);
        den1 += __shfl_xor(den1, m, 64);
        den2 += __shfl_xor(den2, m, 64);
        den3 += __shfl_xor(den3, m, 64);
    }
    float d = (comp == 0) ? den0 : (comp == 1) ? den1 : (comp == 2) ? den2 : den3;
    float4 b = ((const float4*)bg)[lane];
    float o0 = a0 / d + b.x;
    float o1 = a1 / d + b.y;
    float o2 = a2 / d + b.z;
    float o3 = a3 / d + b.w;
    o0 = o0 > 0.f ? o0 : __expf(o0) - 1.f;
    o1 = o1 > 0.f ? o1 : __expf(o1) - 1.f;
    o2 = o2 > 0.f ? o2 : __expf(o2) - 1.f;
    o3 = o3 > 0.f ? o3 : __expf(o3) - 1.f;
    ushort4 u;
    u.x = __half_as_ushort(__float2half(o0));
    u.y = __half_as_ushort(__float2half(o1));
    u.z = __half_as_ushort(__float2half(o2));
    u.w = __half_as_ushort(__float2half(o3));
    ((ushort4*)xg)[(size_t)node * 64 + lane] = u;
    if (lane == 0) dinv[node] = rsqrtf((float)(s1 - s0));
}

// ---------------- GCN + classifier head fused, packed b64 + fma_mix ----------------
__global__ __launch_bounds__(256) void gcn_head(const ushort* __restrict__ xw_half,
                                                const int* __restrict__ row_start,
                                                const int* __restrict__ csr_src,
                                                const float* __restrict__ dinv,
                                                const float* __restrict__ bc,
                                                const float* __restrict__ Wl,
                                                const float* __restrict__ bl,
                                                float* __restrict__ out) {
    __shared__ int2 lds_ow[4][64];   // {byte_off, w_bits}
    const int wid  = threadIdx.x >> 6;
    const int lane = threadIdx.x & 63;
    const int node = blockIdx.x * 4 + wid;
    if (node >= NN) return;
    const int s0 = row_start[node], s1 = row_start[node + 1];
    const float di = dinv[node];
    float ax = 0.f, ay = 0.f;
    const char* xwlane = (const char*)xw_half + lane * 4;

    for (int e = s0; e < s1; e += 64) {
        const int m = min(64, s1 - e);
        if (lane < m) {
            int s = csr_src[e + lane];
            lds_ow[wid][lane] = make_int2(s * 256, __float_as_int(dinv[s] * di));
        }
        asm volatile("s_waitcnt lgkmcnt(0)" ::: "memory");
        int j = 0;
        for (; j + 4 <= m; j += 4) {
            int2 ow0 = lds_ow[wid][j];
            int2 ow1 = lds_ow[wid][j + 1];
            int2 ow2 = lds_ow[wid][j + 2];
            int2 ow3 = lds_ow[wid][j + 3];
            uint v0 = *(const uint*)(xwlane + ow0.x);
            uint v1 = *(const uint*)(xwlane + ow1.x);
            uint v2 = *(const uint*)(xwlane + ow2.x);
            uint v3 = *(const uint*)(xwlane + ow3.x);
            float w0 = __int_as_float(ow0.y);
            float w1 = __int_as_float(ow1.y);
            float w2 = __int_as_float(ow2.y);
            float w3 = __int_as_float(ow3.y);
            FMA_MIX_LO(ax, v0, w0); FMA_MIX_HI(ay, v0, w0);
            FMA_MIX_LO(ax, v1, w1); FMA_MIX_HI(ay, v1, w1);
            FMA_MIX_LO(ax, v2, w2); FMA_MIX_HI(ay, v2, w2);
            FMA_MIX_LO(ax, v3, w3); FMA_MIX_HI(ay, v3, w3);
        }
        for (; j < m; ++j) {
            int2 ow = lds_ow[wid][j];
            uint v = *(const uint*)(xwlane + ow.x);
            float w = __int_as_float(ow.y);
            FMA_MIX_LO(ax, v, w); FMA_MIX_HI(ay, v, w);
        }
        asm volatile("" ::: "memory");
    }
    // xc cols {2*lane, 2*lane+1}
    float2 b = ((const float2*)bc)[lane];
    float o0 = ax + b.x; o0 = o0 > 0.f ? o0 : 0.f;
    float o1 = ay + b.y; o1 = o1 > 0.f ? o1 : 0.f;

    float p[NCLS];
#pragma unroll
    for (int j = 0; j < NCLS; ++j)
        p[j] = o0 * Wl[(2 * lane) * NCLS + j] + o1 * Wl[(2 * lane + 1) * NCLS + j];
#pragma unroll
    for (int m = 32; m >= 1; m >>= 1) {
#pragma unroll
        for (int j = 0; j < NCLS; ++j) p[j] += __shfl_xor(p[j], m, 64);
    }
#pragma unroll
    for (int j = 0; j < NCLS; ++j) p[j] += bl[j];
    float mx = p[0];
#pragma unroll
    for (int j = 1; j < NCLS; ++j) mx = fmaxf(mx, p[j]);
    float s = 0.f;
#pragma unroll
    for (int j = 0; j < NCLS; ++j) s += __expf(p[j] - mx);
    float ls = __logf(s);
    if (lane == 0) {
#pragma unroll
        for (int j = 0; j < NCLS; ++j) out[(size_t)node * NCLS + j] = p[j] - mx - ls;
    }
}

extern "C" void kernel_launch(void* const* d_in, const int* in_sizes, int n_in,
                              void* d_out, int out_size, void* d_ws, size_t ws_size,
                              hipStream_t stream) {
    const float* x       = (const float*)d_in[0];
    const float* Wg      = (const float*)d_in[2];
    const float* att_src = (const float*)d_in[3];
    const float* att_dst = (const float*)d_in[4];
    const float* bg      = (const float*)d_in[5];
    const float* Wc      = (const float*)d_in[6];
    const float* bc      = (const float*)d_in[7];
    const float* Wl      = (const float*)d_in[8];
    const float* bl      = (const float*)d_in[9];
    const int*   ei      = (const int*)d_in[10];
    float* out = (float*)d_out;

    char* p = (char*)d_ws;
    auto alloc = [&](size_t bytes) -> void* {
        void* r = (void*)p;
        p += (bytes + 255) & ~(size_t)255;
        return r;
    };
    ushort* h_half    = (ushort*)alloc((size_t)NN * HC * 2);
    ushort* xg_half   = (ushort*)alloc((size_t)NN * HC * 2);
    ushort* xw_half   = (ushort*)alloc((size_t)NN * HID * 2);
    float*  a_s       = (float*)alloc((size_t)NN * 4 * 4);
    float*  a_d       = (float*)alloc((size_t)NN * 4 * 4);
    int*    deg       = (int*)alloc((size_t)NN * 4);
    float*  dinv      = (float*)alloc((size_t)NN * 4);
    int*    row_start = (int*)alloc((size_t)(NN + 1) * 4);
    int*    cursor    = (int*)alloc((size_t)NN * 4);
    int*    csr_src   = (int*)alloc((size_t)E2 * 4);
    int*    blocksum  = (int*)alloc(256 * 4);
    ushort* wgt       = (ushort*)alloc((size_t)HC * FIN * 2);
    ushort* wct       = (ushort*)alloc((size_t)HID * HC * 2);

    hipMemsetAsync(deg, 0, (size_t)NN * 4, stream);
    hipMemsetAsync(cursor, 0, (size_t)NN * 4, stream);

    prep_kernel<<<128, 256, 0, stream>>>(Wg, Wc, wgt, wct);
    gemm1_mfma<<<625, 256, 0, stream>>>(x, wgt, att_src, att_dst, h_half, a_s, a_d);

    deg_kernel<<<(EE / 4 + 255) / 256, 256, 0, stream>>>(ei, deg);
    scan_a<<<(NN + 255) / 256, 256, 0, stream>>>(deg, row_start, blocksum);
    scan_b<<<1, 256, 0, stream>>>(blocksum, (NN + 255) / 256);
    scan_c<<<(NN + 255) / 256, 256, 0, stream>>>(row_start, blocksum);
    scatter_kernel<<<(E2 + 255) / 256, 256, 0, stream>>>(ei, row_start, cursor, csr_src);

    gat_half<<<(NN + 3) / 4, 256, 0, stream>>>(h_half, a_s, a_d, row_start, csr_src, bg, xg_half, dinv);
    gemm2_mfma<<<625, 256, 0, stream>>>(xg_half, wct, xw_half);
    gcn_head<<<(NN + 3) / 4, 256, 0, stream>>>(xw_half, row_start, csr_src, dinv, bc, Wl, bl, out);
}